// Round 10
// baseline (7186.675 us; speedup 1.0000x reference)
//
#include <hip/hip_runtime.h>
#include <hip/hip_bf16.h>
#include <stdint.h>

// GeometricGNN on MI355X. R=2048, APR=8, H=512, HEADS=4, HD=128, SD=28.
// Round 10: instrumented scalar verification build.
//  - host-side in_sizes / n_in / ws_size checks -> diagnostic constant in out[0]
//  - all loads sanitized (non-finite -> 0)
//  - adaptive footprint: fp32 qkv (18.1MB) or bf16 qkv (11.8MB)
//  - exact fp32 softmax pipeline, flag-aware fp32/bf16 input reads

#define R_ 2048
#define APR_ 8
#define H_ 512
#define HEADS_ 4
#define HD_ 128
#define FA_LD 544

static __device__ __forceinline__ float bf2f(unsigned short u) {
    union { unsigned int i; float f; } c; c.i = ((unsigned int)u) << 16; return c.f;
}
static __device__ __forceinline__ unsigned short f2bf(float f) {
    union { float f; unsigned int i; } c; c.f = f;
    unsigned int r = c.i + 0x7fffu + ((c.i >> 16) & 1u);   // RNE
    return (unsigned short)(r >> 16);
}
// flag-aware, sanitized load of logical element i of a float input array
static __device__ __forceinline__ float loadf(const void* p, size_t i, bool f32) {
    float v = f32 ? ((const float*)p)[i] : bf2f(((const unsigned short*)p)[i]);
    return (v == v && fabsf(v) < 1e30f) ? v : 0.f;
}

// ---------------------------------------------------------------- diag
__global__ void diag(unsigned short* out, float val) {
    if (threadIdx.x == 0 && blockIdx.x == 0) out[0] = f2bf(val);
}

// ---------------------------------------------------------------- dtype detect (d_in[0])
__global__ void detect_dtype(const unsigned short* __restrict__ nf, int* flag) {
    __shared__ int bad;
    if (threadIdx.x == 0) bad = 0;
    __syncthreads();
    int cnt = 0;
    for (int i = threadIdx.x; i < 8192; i += 256) {
        unsigned e = (nf[i] >> 7) & 0xFFu;
        if (e >= 0xC0u) cnt++;
    }
    atomicAdd(&bad, cnt);
    __syncthreads();
    if (threadIdx.x == 0) *flag = (bad > 16) ? 1 : 0;
}

// ---------------------------------------------------------------- gather + frames
__global__ void gather_frames(const void* __restrict__ pos,
                              const int* __restrict__ atype,
                              const int* __restrict__ flag,
                              int* __restrict__ cai, float* __restrict__ ca,
                              float* __restrict__ cb, float* __restrict__ fr,
                              float* __restrict__ maskf)
{
    int r = blockIdx.x * blockDim.x + threadIdx.x;
    if (r >= R_) return;
    bool f32 = *flag != 0;
    int base = r * APR_;
    float caP[3] = {0,0,0}, cbP[3] = {0,0,0};
    int idx = base; bool h0=false, h1=false, h2=false;
    for (int a = 0; a < APR_; a++) {
        int t = atype[base + a];
        if (t == 0) h0 = true;
        if (t == 2) h2 = true;
        if (t == 1) { h1 = true; idx = base + a;
            for (int j = 0; j < 3; j++) caP[j] += loadf(pos, (size_t)(base+a)*3 + j, f32); }
        if (t == 4) {
            for (int j = 0; j < 3; j++) cbP[j] += loadf(pos, (size_t)(base+a)*3 + j, f32); }
    }
    float s = fabsf(cbP[0]) + fabsf(cbP[1]) + fabsf(cbP[2]);
    if (s < 1e-6f) { cbP[0]=caP[0]; cbP[1]=caP[1]; cbP[2]=caP[2]; }
    float e1[3] = { cbP[0]-caP[0], cbP[1]-caP[1], cbP[2]-caP[2] };
    float n1 = sqrtf(e1[0]*e1[0] + e1[1]*e1[1] + e1[2]*e1[2]);
    float e1u[3] = { e1[0], e1[1], e1[2] };
    if (n1 > 1e-6f) { float iv = 1.f / fmaxf(n1, 1e-6f); e1u[0]*=iv; e1u[1]*=iv; e1u[2]*=iv; }
    float e2a[3] = { e1u[1], -e1u[0], 0.f };
    float n2a = sqrtf(e2a[0]*e2a[0] + e2a[1]*e2a[1]);
    float e2b[3] = { -e1u[2], 0.f, e1u[0] };
    float n2b = sqrtf(e2b[0]*e2b[0] + e2b[2]*e2b[2]);
    bool useb = n2a < 1e-6f;
    float e2[3] = { useb?e2b[0]:e2a[0], useb?e2b[1]:e2a[1], useb?e2b[2]:e2a[2] };
    float n2 = useb ? n2b : n2a;
    float iv2 = 1.f / fmaxf(n2, 1e-6f);
    float e2u[3] = { e2[0]*iv2, e2[1]*iv2, e2[2]*iv2 };
    float e3[3] = { e1u[1]*e2u[2]-e1u[2]*e2u[1],
                    e1u[2]*e2u[0]-e1u[0]*e2u[2],
                    e1u[0]*e2u[1]-e1u[1]*e2u[0] };
    bool ok = (r < R_-1) && (n1 > 1e-6f) && (n2 > 1e-6f);
    float F[9];
    if (ok) { F[0]=e1u[0]; F[1]=e2u[0]; F[2]=e3[0];
              F[3]=e1u[1]; F[4]=e2u[1]; F[5]=e3[1];
              F[6]=e1u[2]; F[7]=e2u[2]; F[8]=e3[2]; }
    else    { F[0]=1;F[1]=0;F[2]=0; F[3]=0;F[4]=1;F[5]=0; F[6]=0;F[7]=0;F[8]=1; }
    cai[r] = idx;
    for (int j = 0; j < 3; j++) { ca[r*3+j] = caP[j]; cb[r*3+j] = cbP[j]; }
    for (int j = 0; j < 9; j++) fr[r*9+j] = F[j];
    maskf[r] = (h0 && h1 && h2) ? 1.f : 0.f;
}

// ---------------------------------------------------------------- QKV (naive scalar)
__global__ __launch_bounds__(256) void qkv_naive(
    const void* __restrict__ nf, const int* __restrict__ cai,
    const void* __restrict__ Wq, const void* __restrict__ Wk, const void* __restrict__ Wv,
    const void* __restrict__ bq, const void* __restrict__ bk, const void* __restrict__ bv,
    void* __restrict__ qf, void* __restrict__ kf, void* __restrict__ vf,
    const int* __restrict__ flag, int qkvf32)
{
    const int r = blockIdx.x, tid = threadIdx.x;
    bool f32 = *flag != 0;
    __shared__ float xs[H_];
    size_t s = (size_t)cai[r] * H_;
    for (int c = tid; c < H_; c += 256) xs[c] = loadf(nf, s + c, f32);
    __syncthreads();
    for (int n = tid; n < 3*H_; n += 256) {
        int mat = n >> 9, col = n & 511;
        const void* W = (mat==0) ? Wq : (mat==1) ? Wk : Wv;
        float acc = 0.f;
        for (int k = 0; k < H_; k++) acc += xs[k] * loadf(W, (size_t)k*H_ + col, f32);
        const void* bias = (mat==0) ? bq : (mat==1) ? bk : bv;
        acc += loadf(bias, col, f32);
        void* dst = (mat==0) ? qf : (mat==1) ? kf : vf;
        if (qkvf32) ((float*)dst)[(size_t)r*H_ + col] = acc;
        else        ((unsigned short*)dst)[(size_t)r*H_ + col] = f2bf(acc);
    }
}

static __device__ __forceinline__ float loadqkv(const void* p, size_t i, int f32m) {
    return f32m ? ((const float*)p)[i] : bf2f(((const unsigned short*)p)[i]);
}

// ---------------------------------------------------------------- attention (exact softmax)
__global__ __launch_bounds__(256) void attn_naive(
    const void* __restrict__ qf, const void* __restrict__ kf, const void* __restrict__ vf,
    const float* __restrict__ ca, const float* __restrict__ cb,
    const float* __restrict__ fr, const float* __restrict__ maskf,
    float* __restrict__ fa, int qkvf32)
{
    const int l = blockIdx.x, h = blockIdx.y, tid = threadIdx.x;
    __shared__ float qv[HD_];
    __shared__ float lg[R_];
    __shared__ float sred[256];
    __shared__ float bias3[3];
    if (tid < HD_) qv[tid] = loadqkv(qf, (size_t)l*H_ + h*HD_ + tid, qkvf32);
    __syncthreads();
    const float ml = maskf[l];
    const float mscale = (ml > 0.f) ? 1.f : 0.f;
    for (int k = tid; k < R_; k += 256) {
        float acc = 0.f;
        size_t kr = (size_t)k*H_ + h*HD_;
        for (int d = 0; d < HD_; d++) acc += qv[d] * loadqkv(kf, kr + d, qkvf32);
        lg[k] = (ml > 0.f && maskf[k] > 0.f) ? acc : -1.0e30f;
    }
    __syncthreads();
    float mx = -1.0e30f;
    for (int k = tid; k < R_; k += 256) mx = fmaxf(mx, lg[k]);
    sred[tid] = mx; __syncthreads();
    for (int s = 128; s; s >>= 1) {
        if (tid < s) sred[tid] = fmaxf(sred[tid], sred[tid+s]);
        __syncthreads();
    }
    float rmax = sred[0]; __syncthreads();
    float sm = 0.f;
    for (int k = tid; k < R_; k += 256) { float e = expf(lg[k] - rmax); lg[k] = e; sm += e; }
    sred[tid] = sm; __syncthreads();
    for (int s = 128; s; s >>= 1) {
        if (tid < s) sred[tid] += sred[tid+s];
        __syncthreads();
    }
    float den = sred[0]; __syncthreads();
    float iden = (den > 0.f) ? 1.f/den : 0.f;
    for (int k = tid; k < R_; k += 256) lg[k] = mscale * (lg[k] * iden);
    __syncthreads();
    if (tid < HD_) {
        float o = 0.f;
        for (int k = 0; k < R_; k++) o += lg[k] * loadqkv(vf, (size_t)k*H_ + h*HD_ + tid, qkvf32);
        fa[(size_t)l*FA_LD + h*HD_ + tid] = o;
    }
    float b0=0.f, b1=0.f, b2=0.f;
    const float cbl0 = cb[l*3+0], cbl1 = cb[l*3+1], cbl2 = cb[l*3+2];
    for (int k = tid; k < R_; k += 256) {
        float a = lg[k];
        b0 += a * (cbl0 - ca[k*3+0]);
        b1 += a * (cbl1 - ca[k*3+1]);
        b2 += a * (cbl2 - ca[k*3+2]);
    }
    sred[tid] = b0; __syncthreads();
    for (int s = 128; s; s >>= 1) { if (tid < s) sred[tid] += sred[tid+s]; __syncthreads(); }
    if (tid == 0) bias3[0] = sred[0];
    __syncthreads();
    sred[tid] = b1; __syncthreads();
    for (int s = 128; s; s >>= 1) { if (tid < s) sred[tid] += sred[tid+s]; __syncthreads(); }
    if (tid == 0) bias3[1] = sred[0];
    __syncthreads();
    sred[tid] = b2; __syncthreads();
    for (int s = 128; s; s >>= 1) { if (tid < s) sred[tid] += sred[tid+s]; __syncthreads(); }
    if (tid == 0) bias3[2] = sred[0];
    __syncthreads();
    if (tid == 0) {
        float B0 = bias3[0], B1 = bias3[1], B2 = bias3[2];
        float dist = sqrtf(B0*B0 + B1*B1 + B2*B2);
        const float* F = fr + (size_t)l*9;
        float p0 = F[0]*B0 + F[1]*B1 + F[2]*B2;
        float p1 = F[3]*B0 + F[4]*B1 + F[5]*B2;
        float p2 = F[6]*B0 + F[7]*B1 + F[8]*B2;
        float pn = sqrtf(p0*p0 + p1*p1 + p2*p2) + 1e-10f;
        size_t rb = (size_t)l * FA_LD;
        fa[rb + 512 + h*3 + 0] = p0;
        fa[rb + 512 + h*3 + 1] = p1;
        fa[rb + 512 + h*3 + 2] = p2;
        fa[rb + 524 + h]       = dist;
        fa[rb + 528 + h*3 + 0] = p0/pn;
        fa[rb + 528 + h*3 + 1] = p1/pn;
        fa[rb + 528 + h*3 + 2] = p2/pn;
        if (h == 0) { fa[rb+540]=0.f; fa[rb+541]=0.f; fa[rb+542]=0.f; fa[rb+543]=0.f; }
    }
}

// ---------------------------------------------------------------- Wo (naive scalar)
__global__ __launch_bounds__(256) void wo_naive(
    const float* __restrict__ fa, const void* __restrict__ Wo,
    const void* __restrict__ bo, float* __restrict__ Y,
    const int* __restrict__ flag)
{
    const int r = blockIdx.x, tid = threadIdx.x;
    bool f32 = *flag != 0;
    __shared__ float fs[FA_LD];
    for (int c = tid; c < FA_LD; c += 256) fs[c] = fa[(size_t)r*FA_LD + c];
    __syncthreads();
    for (int n = tid; n < H_; n += 256) {
        float acc = 0.f;
        for (int k = 0; k < 540; k++) acc += fs[k] * loadf(Wo, (size_t)k*H_ + n, f32);
        Y[(size_t)r*H_ + n] = acc + loadf(bo, n, f32);
    }
}

// ---------------------------------------------------------------- relu+LN1+mask+res+LN2
__global__ __launch_bounds__(256) void final_ln(
    const float* __restrict__ Y, const void* __restrict__ nf,
    const int* __restrict__ cai, const float* __restrict__ maskf,
    const void* __restrict__ g1, const void* __restrict__ b1,
    const void* __restrict__ g2, const void* __restrict__ b2,
    void* __restrict__ out, const int* __restrict__ flag)
{
    const int tid = threadIdx.x, lane = tid & 63, wave = tid >> 6;
    const int r = blockIdx.x * 4 + wave;
    bool f32 = *flag != 0;
    const float mk = maskf[r];
    const size_t xrow = (size_t)cai[r] * H_;
    float y[8], s1 = 0.f, s2 = 0.f;
    #pragma unroll
    for (int i = 0; i < 8; i++) {
        int c = lane + i*64;
        float v = fmaxf(Y[(size_t)r*H_ + c], 0.f);
        y[i] = v; s1 += v; s2 += v*v;
    }
    #pragma unroll
    for (int off = 32; off; off >>= 1) { s1 += __shfl_xor(s1, off); s2 += __shfl_xor(s2, off); }
    float mu = s1 * (1.f/H_);
    float var = s2 * (1.f/H_) - mu*mu;
    float rstd = rsqrtf(fmaxf(var, 0.f) + 1e-5f);
    float t[8], u1 = 0.f, u2 = 0.f;
    #pragma unroll
    for (int i = 0; i < 8; i++) {
        int c = lane + i*64;
        float hh = (y[i]-mu)*rstd*loadf(g1, c, f32) + loadf(b1, c, f32);
        hh *= mk;
        float tv = loadf(nf, xrow + c, f32) + hh;
        t[i] = tv; u1 += tv; u2 += tv*tv;
    }
    #pragma unroll
    for (int off = 32; off; off >>= 1) { u1 += __shfl_xor(u1, off); u2 += __shfl_xor(u2, off); }
    float mu2 = u1 * (1.f/H_);
    float var2 = u2 * (1.f/H_) - mu2*mu2;
    float rstd2 = rsqrtf(fmaxf(var2, 0.f) + 1e-5f);
    #pragma unroll
    for (int i = 0; i < 8; i++) {
        int c = lane + i*64;
        float ov = (t[i]-mu2)*rstd2*loadf(g2, c, f32) + loadf(b2, c, f32);
        if (f32) ((float*)out)[(size_t)r*H_ + c] = ov;
        else ((unsigned short*)out)[(size_t)r*H_ + c] = f2bf(ov);
    }
}

// ---------------------------------------------------------------- launch
extern "C" void kernel_launch(void* const* d_in, const int* in_sizes, int n_in,
                              void* d_out, int out_size, void* d_ws, size_t ws_size,
                              hipStream_t stream)
{
    // ---- host-side signature verification (debug channel via out[0]) ----
    static const int expected[16] = {
        8388608, 49152, 262144, 512, 262144, 512, 262144, 512,
        276480, 512, 512, 512, 512, 512, 16384, 16384
    };
    if (n_in != 16) {
        diag<<<dim3(1), dim3(64), 0, stream>>>((unsigned short*)d_out, 1000.f + n_in);
        return;
    }
    for (int i = 0; i < 16; i++) {
        if (in_sizes[i] != expected[i]) {
            diag<<<dim3(1), dim3(64), 0, stream>>>((unsigned short*)d_out, 2000.f + 10.f*i);
            return;
        }
    }
    const size_t smallEnd = 1u << 20;               // 1MB for small buffers
    const size_t qkvF32Bytes = (size_t)R_*H_*4;     // 4MB each
    const size_t qkvBF16Bytes = (size_t)R_*H_*2;    // 2MB each
    const size_t faBytes = (size_t)R_*FA_LD*4;      // 4.46MB
    const size_t needF32  = smallEnd + 3*qkvF32Bytes + faBytes;   // ~18.1MB
    const size_t needBF16 = smallEnd + 3*qkvBF16Bytes + faBytes;  // ~11.8MB
    if (ws_size < needBF16) {
        diag<<<dim3(1), dim3(64), 0, stream>>>((unsigned short*)d_out, 3000.f);
        return;
    }
    const int qkvf32 = (ws_size >= needF32) ? 1 : 0;
    const size_t qkvBytes = qkvf32 ? qkvF32Bytes : qkvBF16Bytes;

    const void* nf  = d_in[0];
    const void* pos = d_in[1];
    const void* Wq  = d_in[2];  const void* bq = d_in[3];
    const void* Wk  = d_in[4];  const void* bk = d_in[5];
    const void* Wv  = d_in[6];  const void* bv = d_in[7];
    const void* Wo  = d_in[8];  const void* bo = d_in[9];
    const void* g1  = d_in[10]; const void* b1 = d_in[11];
    const void* g2  = d_in[12]; const void* b2 = d_in[13];
    const int* atype = (const int*)d_in[14];

    char* ws = (char*)d_ws;
    int*   flag  = (int*)  (ws + 0);
    int*   cai   = (int*)  (ws + 1024);
    float* ca    = (float*)(ws + 9216);
    float* cb    = (float*)(ws + 33792);
    float* fr    = (float*)(ws + 58368);
    float* maskf = (float*)(ws + 132096);
    void*  qf = ws + smallEnd;
    void*  kf = ws + smallEnd + qkvBytes;
    void*  vf = ws + smallEnd + 2*qkvBytes;
    float* fa = (float*)(ws + smallEnd + 3*qkvBytes);
    float* Y  = (float*)qf;   // aliases qf(+kf) — both dead after attn

    detect_dtype<<<dim3(1), dim3(256), 0, stream>>>((const unsigned short*)nf, flag);
    gather_frames<<<dim3(8), dim3(256), 0, stream>>>(pos, atype, flag, cai, ca, cb, fr, maskf);
    qkv_naive<<<dim3(R_), dim3(256), 0, stream>>>(nf, cai, Wq, Wk, Wv, bq, bk, bv,
                                                  qf, kf, vf, flag, qkvf32);
    attn_naive<<<dim3(R_, HEADS_), dim3(256), 0, stream>>>(qf, kf, vf, ca, cb, fr, maskf,
                                                           fa, qkvf32);
    wo_naive<<<dim3(R_), dim3(256), 0, stream>>>(fa, Wo, bo, Y, flag);
    final_ln<<<dim3(512), dim3(256), 0, stream>>>(Y, nf, cai, maskf, g1, b1, g2, b2,
                                                  d_out, flag);
}

// Round 14
// 2128.308 us; speedup vs baseline: 3.3767x; 3.3767x over previous
//
#include <hip/hip_runtime.h>
#include <hip/hip_bf16.h>
#include <stdint.h>

// GeometricGNN on MI355X. R=2048, APR=8, H=512, HEADS=4, HD=128, SD=28.
// Round 14: R10 (the ONLY passing build, 7187us) byte-for-byte, with exactly
// one patch: attn_naive's o-accumulation is LDS-tiled (V staged in 64-key
// tiles, 256 threads accumulate) and the logits loop uses float4 K reads.
// Everything else — sanitized loads, flag machinery, ws layout — VERBATIM.

#define R_ 2048
#define APR_ 8
#define H_ 512
#define HEADS_ 4
#define HD_ 128
#define FA_LD 544

typedef __attribute__((ext_vector_type(4))) float f32x4;

static __device__ __forceinline__ float bf2f(unsigned short u) {
    union { unsigned int i; float f; } c; c.i = ((unsigned int)u) << 16; return c.f;
}
static __device__ __forceinline__ unsigned short f2bf(float f) {
    union { float f; unsigned int i; } c; c.f = f;
    unsigned int r = c.i + 0x7fffu + ((c.i >> 16) & 1u);   // RNE
    return (unsigned short)(r >> 16);
}
// flag-aware, sanitized load of logical element i of a float input array
static __device__ __forceinline__ float loadf(const void* p, size_t i, bool f32) {
    float v = f32 ? ((const float*)p)[i] : bf2f(((const unsigned short*)p)[i]);
    return (v == v && fabsf(v) < 1e30f) ? v : 0.f;
}

// ---------------------------------------------------------------- diag
__global__ void diag(unsigned short* out, float val) {
    if (threadIdx.x == 0 && blockIdx.x == 0) out[0] = f2bf(val);
}

// ---------------------------------------------------------------- dtype detect (d_in[0])
__global__ void detect_dtype(const unsigned short* __restrict__ nf, int* flag) {
    __shared__ int bad;
    if (threadIdx.x == 0) bad = 0;
    __syncthreads();
    int cnt = 0;
    for (int i = threadIdx.x; i < 8192; i += 256) {
        unsigned e = (nf[i] >> 7) & 0xFFu;
        if (e >= 0xC0u) cnt++;
    }
    atomicAdd(&bad, cnt);
    __syncthreads();
    if (threadIdx.x == 0) *flag = (bad > 16) ? 1 : 0;
}

// ---------------------------------------------------------------- gather + frames
__global__ void gather_frames(const void* __restrict__ pos,
                              const int* __restrict__ atype,
                              const int* __restrict__ flag,
                              int* __restrict__ cai, float* __restrict__ ca,
                              float* __restrict__ cb, float* __restrict__ fr,
                              float* __restrict__ maskf)
{
    int r = blockIdx.x * blockDim.x + threadIdx.x;
    if (r >= R_) return;
    bool f32 = *flag != 0;
    int base = r * APR_;
    float caP[3] = {0,0,0}, cbP[3] = {0,0,0};
    int idx = base; bool h0=false, h1=false, h2=false;
    for (int a = 0; a < APR_; a++) {
        int t = atype[base + a];
        if (t == 0) h0 = true;
        if (t == 2) h2 = true;
        if (t == 1) { h1 = true; idx = base + a;
            for (int j = 0; j < 3; j++) caP[j] += loadf(pos, (size_t)(base+a)*3 + j, f32); }
        if (t == 4) {
            for (int j = 0; j < 3; j++) cbP[j] += loadf(pos, (size_t)(base+a)*3 + j, f32); }
    }
    float s = fabsf(cbP[0]) + fabsf(cbP[1]) + fabsf(cbP[2]);
    if (s < 1e-6f) { cbP[0]=caP[0]; cbP[1]=caP[1]; cbP[2]=caP[2]; }
    float e1[3] = { cbP[0]-caP[0], cbP[1]-caP[1], cbP[2]-caP[2] };
    float n1 = sqrtf(e1[0]*e1[0] + e1[1]*e1[1] + e1[2]*e1[2]);
    float e1u[3] = { e1[0], e1[1], e1[2] };
    if (n1 > 1e-6f) { float iv = 1.f / fmaxf(n1, 1e-6f); e1u[0]*=iv; e1u[1]*=iv; e1u[2]*=iv; }
    float e2a[3] = { e1u[1], -e1u[0], 0.f };
    float n2a = sqrtf(e2a[0]*e2a[0] + e2a[1]*e2a[1]);
    float e2b[3] = { -e1u[2], 0.f, e1u[0] };
    float n2b = sqrtf(e2b[0]*e2b[0] + e2b[2]*e2b[2]);
    bool useb = n2a < 1e-6f;
    float e2[3] = { useb?e2b[0]:e2a[0], useb?e2b[1]:e2a[1], useb?e2b[2]:e2a[2] };
    float n2 = useb ? n2b : n2a;
    float iv2 = 1.f / fmaxf(n2, 1e-6f);
    float e2u[3] = { e2[0]*iv2, e2[1]*iv2, e2[2]*iv2 };
    float e3[3] = { e1u[1]*e2u[2]-e1u[2]*e2u[1],
                    e1u[2]*e2u[0]-e1u[0]*e2u[2],
                    e1u[0]*e2u[1]-e1u[1]*e2u[0] };
    bool ok = (r < R_-1) && (n1 > 1e-6f) && (n2 > 1e-6f);
    float F[9];
    if (ok) { F[0]=e1u[0]; F[1]=e2u[0]; F[2]=e3[0];
              F[3]=e1u[1]; F[4]=e2u[1]; F[5]=e3[1];
              F[6]=e1u[2]; F[7]=e2u[2]; F[8]=e3[2]; }
    else    { F[0]=1;F[1]=0;F[2]=0; F[3]=0;F[4]=1;F[5]=0; F[6]=0;F[7]=0;F[8]=1; }
    cai[r] = idx;
    for (int j = 0; j < 3; j++) { ca[r*3+j] = caP[j]; cb[r*3+j] = cbP[j]; }
    for (int j = 0; j < 9; j++) fr[r*9+j] = F[j];
    maskf[r] = (h0 && h1 && h2) ? 1.f : 0.f;
}

// ---------------------------------------------------------------- QKV (naive scalar)
__global__ __launch_bounds__(256) void qkv_naive(
    const void* __restrict__ nf, const int* __restrict__ cai,
    const void* __restrict__ Wq, const void* __restrict__ Wk, const void* __restrict__ Wv,
    const void* __restrict__ bq, const void* __restrict__ bk, const void* __restrict__ bv,
    void* __restrict__ qf, void* __restrict__ kf, void* __restrict__ vf,
    const int* __restrict__ flag, int qkvf32)
{
    const int r = blockIdx.x, tid = threadIdx.x;
    bool f32 = *flag != 0;
    __shared__ float xs[H_];
    size_t s = (size_t)cai[r] * H_;
    for (int c = tid; c < H_; c += 256) xs[c] = loadf(nf, s + c, f32);
    __syncthreads();
    for (int n = tid; n < 3*H_; n += 256) {
        int mat = n >> 9, col = n & 511;
        const void* W = (mat==0) ? Wq : (mat==1) ? Wk : Wv;
        float acc = 0.f;
        for (int k = 0; k < H_; k++) acc += xs[k] * loadf(W, (size_t)k*H_ + col, f32);
        const void* bias = (mat==0) ? bq : (mat==1) ? bk : bv;
        acc += loadf(bias, col, f32);
        void* dst = (mat==0) ? qf : (mat==1) ? kf : vf;
        if (qkvf32) ((float*)dst)[(size_t)r*H_ + col] = acc;
        else        ((unsigned short*)dst)[(size_t)r*H_ + col] = f2bf(acc);
    }
}

static __device__ __forceinline__ float loadqkv(const void* p, size_t i, int f32m) {
    return f32m ? ((const float*)p)[i] : bf2f(((const unsigned short*)p)[i]);
}

// ---------------------------------------------------------------- attention (exact softmax)
// R10 verbatim EXCEPT: (1) float4 K reads in the logits loop (fp32 mode),
// (2) o-accumulation LDS-tiled (V staged 64 keys at a time, 256 threads).
__global__ __launch_bounds__(256) void attn_naive(
    const void* __restrict__ qf, const void* __restrict__ kf, const void* __restrict__ vf,
    const float* __restrict__ ca, const float* __restrict__ cb,
    const float* __restrict__ fr, const float* __restrict__ maskf,
    float* __restrict__ fa, int qkvf32)
{
    const int l = blockIdx.x, h = blockIdx.y, tid = threadIdx.x;
    __shared__ __align__(16) float qv[HD_];
    __shared__ float lg[R_];
    __shared__ float sred[256];
    __shared__ float bias3[3];
    __shared__ __align__(16) float Vsh[64][128];
    if (tid < HD_) qv[tid] = loadqkv(qf, (size_t)l*H_ + h*HD_ + tid, qkvf32);
    __syncthreads();
    const float ml = maskf[l];
    const float mscale = (ml > 0.f) ? 1.f : 0.f;
    for (int k = tid; k < R_; k += 256) {
        float acc = 0.f;
        if (qkvf32) {
            const float* kr = (const float*)kf + (size_t)k*H_ + h*HD_;
            for (int d4 = 0; d4 < 32; d4++) {
                f32x4 kv = *(const f32x4*)(kr + d4*4);
                f32x4 qq = *(const f32x4*)&qv[d4*4];
                acc += qq[0]*kv[0] + qq[1]*kv[1] + qq[2]*kv[2] + qq[3]*kv[3];
            }
        } else {
            size_t kr = (size_t)k*H_ + h*HD_;
            for (int d = 0; d < HD_; d++) acc += qv[d] * loadqkv(kf, kr + d, qkvf32);
        }
        lg[k] = (ml > 0.f && maskf[k] > 0.f) ? acc : -1.0e30f;
    }
    __syncthreads();
    float mx = -1.0e30f;
    for (int k = tid; k < R_; k += 256) mx = fmaxf(mx, lg[k]);
    sred[tid] = mx; __syncthreads();
    for (int s = 128; s; s >>= 1) {
        if (tid < s) sred[tid] = fmaxf(sred[tid], sred[tid+s]);
        __syncthreads();
    }
    float rmax = sred[0]; __syncthreads();
    float sm = 0.f;
    for (int k = tid; k < R_; k += 256) { float e = expf(lg[k] - rmax); lg[k] = e; sm += e; }
    sred[tid] = sm; __syncthreads();
    for (int s = 128; s; s >>= 1) {
        if (tid < s) sred[tid] += sred[tid+s];
        __syncthreads();
    }
    float den = sred[0]; __syncthreads();
    float iden = (den > 0.f) ? 1.f/den : 0.f;
    for (int k = tid; k < R_; k += 256) lg[k] = mscale * (lg[k] * iden);
    __syncthreads();
    // ---- patched o-accumulation: V staged through LDS, all 256 threads ----
    const int dd = tid & 127, kh = tid >> 7;   // kh in {0,1}
    float oacc = 0.f;
    for (int kt2 = 0; kt2 < R_/64; kt2++) {
        const int kb2 = kt2 * 64;
        __syncthreads();
        for (int i = tid; i < 64*32; i += 256) {
            int kk = i >> 5, d4 = i & 31;
            if (qkvf32) {
                *(f32x4*)&Vsh[kk][d4*4] =
                    *(const f32x4*)((const float*)vf + (size_t)(kb2+kk)*H_ + h*HD_ + d4*4);
            } else {
                const unsigned short* vb = (const unsigned short*)vf;
                size_t base = (size_t)(kb2+kk)*H_ + h*HD_ + d4*4;
                Vsh[kk][d4*4+0] = bf2f(vb[base+0]);
                Vsh[kk][d4*4+1] = bf2f(vb[base+1]);
                Vsh[kk][d4*4+2] = bf2f(vb[base+2]);
                Vsh[kk][d4*4+3] = bf2f(vb[base+3]);
            }
        }
        __syncthreads();
        #pragma unroll 8
        for (int kk = 0; kk < 32; kk++)
            oacc += lg[kb2 + kh*32 + kk] * Vsh[kh*32 + kk][dd];
    }
    __syncthreads();
    sred[tid] = oacc;
    __syncthreads();
    if (tid < HD_)
        fa[(size_t)l*FA_LD + h*HD_ + tid] = sred[tid] + sred[tid + 128];
    __syncthreads();
    // ---- end patch ----
    float b0=0.f, b1=0.f, b2=0.f;
    const float cbl0 = cb[l*3+0], cbl1 = cb[l*3+1], cbl2 = cb[l*3+2];
    for (int k = tid; k < R_; k += 256) {
        float a = lg[k];
        b0 += a * (cbl0 - ca[k*3+0]);
        b1 += a * (cbl1 - ca[k*3+1]);
        b2 += a * (cbl2 - ca[k*3+2]);
    }
    sred[tid] = b0; __syncthreads();
    for (int s = 128; s; s >>= 1) { if (tid < s) sred[tid] += sred[tid+s]; __syncthreads(); }
    if (tid == 0) bias3[0] = sred[0];
    __syncthreads();
    sred[tid] = b1; __syncthreads();
    for (int s = 128; s; s >>= 1) { if (tid < s) sred[tid] += sred[tid+s]; __syncthreads(); }
    if (tid == 0) bias3[1] = sred[0];
    __syncthreads();
    sred[tid] = b2; __syncthreads();
    for (int s = 128; s; s >>= 1) { if (tid < s) sred[tid] += sred[tid+s]; __syncthreads(); }
    if (tid == 0) bias3[2] = sred[0];
    __syncthreads();
    if (tid == 0) {
        float B0 = bias3[0], B1 = bias3[1], B2 = bias3[2];
        float dist = sqrtf(B0*B0 + B1*B1 + B2*B2);
        const float* F = fr + (size_t)l*9;
        float p0 = F[0]*B0 + F[1]*B1 + F[2]*B2;
        float p1 = F[3]*B0 + F[4]*B1 + F[5]*B2;
        float p2 = F[6]*B0 + F[7]*B1 + F[8]*B2;
        float pn = sqrtf(p0*p0 + p1*p1 + p2*p2) + 1e-10f;
        size_t rb = (size_t)l * FA_LD;
        fa[rb + 512 + h*3 + 0] = p0;
        fa[rb + 512 + h*3 + 1] = p1;
        fa[rb + 512 + h*3 + 2] = p2;
        fa[rb + 524 + h]       = dist;
        fa[rb + 528 + h*3 + 0] = p0/pn;
        fa[rb + 528 + h*3 + 1] = p1/pn;
        fa[rb + 528 + h*3 + 2] = p2/pn;
        if (h == 0) { fa[rb+540]=0.f; fa[rb+541]=0.f; fa[rb+542]=0.f; fa[rb+543]=0.f; }
    }
}

// ---------------------------------------------------------------- Wo (naive scalar)
__global__ __launch_bounds__(256) void wo_naive(
    const float* __restrict__ fa, const void* __restrict__ Wo,
    const void* __restrict__ bo, float* __restrict__ Y,
    const int* __restrict__ flag)
{
    const int r = blockIdx.x, tid = threadIdx.x;
    bool f32 = *flag != 0;
    __shared__ float fs[FA_LD];
    for (int c = tid; c < FA_LD; c += 256) fs[c] = fa[(size_t)r*FA_LD + c];
    __syncthreads();
    for (int n = tid; n < H_; n += 256) {
        float acc = 0.f;
        for (int k = 0; k < 540; k++) acc += fs[k] * loadf(Wo, (size_t)k*H_ + n, f32);
        Y[(size_t)r*H_ + n] = acc + loadf(bo, n, f32);
    }
}

// ---------------------------------------------------------------- relu+LN1+mask+res+LN2
__global__ __launch_bounds__(256) void final_ln(
    const float* __restrict__ Y, const void* __restrict__ nf,
    const int* __restrict__ cai, const float* __restrict__ maskf,
    const void* __restrict__ g1, const void* __restrict__ b1,
    const void* __restrict__ g2, const void* __restrict__ b2,
    void* __restrict__ out, const int* __restrict__ flag)
{
    const int tid = threadIdx.x, lane = tid & 63, wave = tid >> 6;
    const int r = blockIdx.x * 4 + wave;
    bool f32 = *flag != 0;
    const float mk = maskf[r];
    const size_t xrow = (size_t)cai[r] * H_;
    float y[8], s1 = 0.f, s2 = 0.f;
    #pragma unroll
    for (int i = 0; i < 8; i++) {
        int c = lane + i*64;
        float v = fmaxf(Y[(size_t)r*H_ + c], 0.f);
        y[i] = v; s1 += v; s2 += v*v;
    }
    #pragma unroll
    for (int off = 32; off; off >>= 1) { s1 += __shfl_xor(s1, off); s2 += __shfl_xor(s2, off); }
    float mu = s1 * (1.f/H_);
    float var = s2 * (1.f/H_) - mu*mu;
    float rstd = rsqrtf(fmaxf(var, 0.f) + 1e-5f);
    float t[8], u1 = 0.f, u2 = 0.f;
    #pragma unroll
    for (int i = 0; i < 8; i++) {
        int c = lane + i*64;
        float hh = (y[i]-mu)*rstd*loadf(g1, c, f32) + loadf(b1, c, f32);
        hh *= mk;
        float tv = loadf(nf, xrow + c, f32) + hh;
        t[i] = tv; u1 += tv; u2 += tv*tv;
    }
    #pragma unroll
    for (int off = 32; off; off >>= 1) { u1 += __shfl_xor(u1, off); u2 += __shfl_xor(u2, off); }
    float mu2 = u1 * (1.f/H_);
    float var2 = u2 * (1.f/H_) - mu2*mu2;
    float rstd2 = rsqrtf(fmaxf(var2, 0.f) + 1e-5f);
    #pragma unroll
    for (int i = 0; i < 8; i++) {
        int c = lane + i*64;
        float ov = (t[i]-mu2)*rstd2*loadf(g2, c, f32) + loadf(b2, c, f32);
        if (f32) ((float*)out)[(size_t)r*H_ + c] = ov;
        else ((unsigned short*)out)[(size_t)r*H_ + c] = f2bf(ov);
    }
}

// ---------------------------------------------------------------- launch
extern "C" void kernel_launch(void* const* d_in, const int* in_sizes, int n_in,
                              void* d_out, int out_size, void* d_ws, size_t ws_size,
                              hipStream_t stream)
{
    // ---- host-side signature verification (debug channel via out[0]) ----
    static const int expected[16] = {
        8388608, 49152, 262144, 512, 262144, 512, 262144, 512,
        276480, 512, 512, 512, 512, 512, 16384, 16384
    };
    if (n_in != 16) {
        diag<<<dim3(1), dim3(64), 0, stream>>>((unsigned short*)d_out, 1000.f + n_in);
        return;
    }
    for (int i = 0; i < 16; i++) {
        if (in_sizes[i] != expected[i]) {
            diag<<<dim3(1), dim3(64), 0, stream>>>((unsigned short*)d_out, 2000.f + 10.f*i);
            return;
        }
    }
    const size_t smallEnd = 1u << 20;               // 1MB for small buffers
    const size_t qkvF32Bytes = (size_t)R_*H_*4;     // 4MB each
    const size_t qkvBF16Bytes = (size_t)R_*H_*2;    // 2MB each
    const size_t faBytes = (size_t)R_*FA_LD*4;      // 4.46MB
    const size_t needF32  = smallEnd + 3*qkvF32Bytes + faBytes;   // ~18.1MB
    const size_t needBF16 = smallEnd + 3*qkvBF16Bytes + faBytes;  // ~11.8MB
    if (ws_size < needBF16) {
        diag<<<dim3(1), dim3(64), 0, stream>>>((unsigned short*)d_out, 3000.f);
        return;
    }
    const int qkvf32 = (ws_size >= needF32) ? 1 : 0;
    const size_t qkvBytes = qkvf32 ? qkvF32Bytes : qkvBF16Bytes;

    const void* nf  = d_in[0];
    const void* pos = d_in[1];
    const void* Wq  = d_in[2];  const void* bq = d_in[3];
    const void* Wk  = d_in[4];  const void* bk = d_in[5];
    const void* Wv  = d_in[6];  const void* bv = d_in[7];
    const void* Wo  = d_in[8];  const void* bo = d_in[9];
    const void* g1  = d_in[10]; const void* b1 = d_in[11];
    const void* g2  = d_in[12]; const void* b2 = d_in[13];
    const int* atype = (const int*)d_in[14];

    char* ws = (char*)d_ws;
    int*   flag  = (int*)  (ws + 0);
    int*   cai   = (int*)  (ws + 1024);
    float* ca    = (float*)(ws + 9216);
    float* cb    = (float*)(ws + 33792);
    float* fr    = (float*)(ws + 58368);
    float* maskf = (float*)(ws + 132096);
    void*  qf = ws + smallEnd;
    void*  kf = ws + smallEnd + qkvBytes;
    void*  vf = ws + smallEnd + 2*qkvBytes;
    float* fa = (float*)(ws + smallEnd + 3*qkvBytes);
    float* Y  = (float*)qf;   // aliases qf(+kf) — both dead after attn

    detect_dtype<<<dim3(1), dim3(256), 0, stream>>>((const unsigned short*)nf, flag);
    gather_frames<<<dim3(8), dim3(256), 0, stream>>>(pos, atype, flag, cai, ca, cb, fr, maskf);
    qkv_naive<<<dim3(R_), dim3(256), 0, stream>>>(nf, cai, Wq, Wk, Wv, bq, bk, bv,
                                                  qf, kf, vf, flag, qkvf32);
    attn_naive<<<dim3(R_, HEADS_), dim3(256), 0, stream>>>(qf, kf, vf, ca, cb, fr, maskf,
                                                           fa, qkvf32);
    wo_naive<<<dim3(R_), dim3(256), 0, stream>>>(fa, Wo, bo, Y, flag);
    final_ln<<<dim3(512), dim3(256), 0, stream>>>(Y, nf, cai, maskf, g1, b1, g2, b2,
                                                  d_out, flag);
}

// Round 15
// 908.865 us; speedup vs baseline: 7.9073x; 2.3417x over previous
//
#include <hip/hip_runtime.h>
#include <hip/hip_bf16.h>
#include <stdint.h>

// GeometricGNN on MI355X. R=2048, APR=8, H=512, HEADS=4, HD=128, SD=28.
// Round 15: R14 (passing, 2128us) with ONLY attn replaced: 16-query x 1-head
// blocks, K/V in 32-key LDS tiles, single-pass UNNORMALIZED softmax (fp32-safe,
// guards kept). K/V L2 traffic /16. Everything else byte-identical to R14.

#define R_ 2048
#define APR_ 8
#define H_ 512
#define HEADS_ 4
#define HD_ 128
#define FA_LD 544
#define QT 16
#define KTL 32

typedef __attribute__((ext_vector_type(4))) float f32x4;

static __device__ __forceinline__ float bf2f(unsigned short u) {
    union { unsigned int i; float f; } c; c.i = ((unsigned int)u) << 16; return c.f;
}
static __device__ __forceinline__ unsigned short f2bf(float f) {
    union { float f; unsigned int i; } c; c.f = f;
    unsigned int r = c.i + 0x7fffu + ((c.i >> 16) & 1u);   // RNE
    return (unsigned short)(r >> 16);
}
// flag-aware, sanitized load of logical element i of a float input array
static __device__ __forceinline__ float loadf(const void* p, size_t i, bool f32) {
    float v = f32 ? ((const float*)p)[i] : bf2f(((const unsigned short*)p)[i]);
    return (v == v && fabsf(v) < 1e30f) ? v : 0.f;
}

// ---------------------------------------------------------------- diag
__global__ void diag(unsigned short* out, float val) {
    if (threadIdx.x == 0 && blockIdx.x == 0) out[0] = f2bf(val);
}

// ---------------------------------------------------------------- dtype detect (d_in[0])
__global__ void detect_dtype(const unsigned short* __restrict__ nf, int* flag) {
    __shared__ int bad;
    if (threadIdx.x == 0) bad = 0;
    __syncthreads();
    int cnt = 0;
    for (int i = threadIdx.x; i < 8192; i += 256) {
        unsigned e = (nf[i] >> 7) & 0xFFu;
        if (e >= 0xC0u) cnt++;
    }
    atomicAdd(&bad, cnt);
    __syncthreads();
    if (threadIdx.x == 0) *flag = (bad > 16) ? 1 : 0;
}

// ---------------------------------------------------------------- gather + frames
__global__ void gather_frames(const void* __restrict__ pos,
                              const int* __restrict__ atype,
                              const int* __restrict__ flag,
                              int* __restrict__ cai, float* __restrict__ ca,
                              float* __restrict__ cb, float* __restrict__ fr,
                              float* __restrict__ maskf)
{
    int r = blockIdx.x * blockDim.x + threadIdx.x;
    if (r >= R_) return;
    bool f32 = *flag != 0;
    int base = r * APR_;
    float caP[3] = {0,0,0}, cbP[3] = {0,0,0};
    int idx = base; bool h0=false, h1=false, h2=false;
    for (int a = 0; a < APR_; a++) {
        int t = atype[base + a];
        if (t == 0) h0 = true;
        if (t == 2) h2 = true;
        if (t == 1) { h1 = true; idx = base + a;
            for (int j = 0; j < 3; j++) caP[j] += loadf(pos, (size_t)(base+a)*3 + j, f32); }
        if (t == 4) {
            for (int j = 0; j < 3; j++) cbP[j] += loadf(pos, (size_t)(base+a)*3 + j, f32); }
    }
    float s = fabsf(cbP[0]) + fabsf(cbP[1]) + fabsf(cbP[2]);
    if (s < 1e-6f) { cbP[0]=caP[0]; cbP[1]=caP[1]; cbP[2]=caP[2]; }
    float e1[3] = { cbP[0]-caP[0], cbP[1]-caP[1], cbP[2]-caP[2] };
    float n1 = sqrtf(e1[0]*e1[0] + e1[1]*e1[1] + e1[2]*e1[2]);
    float e1u[3] = { e1[0], e1[1], e1[2] };
    if (n1 > 1e-6f) { float iv = 1.f / fmaxf(n1, 1e-6f); e1u[0]*=iv; e1u[1]*=iv; e1u[2]*=iv; }
    float e2a[3] = { e1u[1], -e1u[0], 0.f };
    float n2a = sqrtf(e2a[0]*e2a[0] + e2a[1]*e2a[1]);
    float e2b[3] = { -e1u[2], 0.f, e1u[0] };
    float n2b = sqrtf(e2b[0]*e2b[0] + e2b[2]*e2b[2]);
    bool useb = n2a < 1e-6f;
    float e2[3] = { useb?e2b[0]:e2a[0], useb?e2b[1]:e2a[1], useb?e2b[2]:e2a[2] };
    float n2 = useb ? n2b : n2a;
    float iv2 = 1.f / fmaxf(n2, 1e-6f);
    float e2u[3] = { e2[0]*iv2, e2[1]*iv2, e2[2]*iv2 };
    float e3[3] = { e1u[1]*e2u[2]-e1u[2]*e2u[1],
                    e1u[2]*e2u[0]-e1u[0]*e2u[2],
                    e1u[0]*e2u[1]-e1u[1]*e2u[0] };
    bool ok = (r < R_-1) && (n1 > 1e-6f) && (n2 > 1e-6f);
    float F[9];
    if (ok) { F[0]=e1u[0]; F[1]=e2u[0]; F[2]=e3[0];
              F[3]=e1u[1]; F[4]=e2u[1]; F[5]=e3[1];
              F[6]=e1u[2]; F[7]=e2u[2]; F[8]=e3[2]; }
    else    { F[0]=1;F[1]=0;F[2]=0; F[3]=0;F[4]=1;F[5]=0; F[6]=0;F[7]=0;F[8]=1; }
    cai[r] = idx;
    for (int j = 0; j < 3; j++) { ca[r*3+j] = caP[j]; cb[r*3+j] = cbP[j]; }
    for (int j = 0; j < 9; j++) fr[r*9+j] = F[j];
    maskf[r] = (h0 && h1 && h2) ? 1.f : 0.f;
}

// ---------------------------------------------------------------- QKV (naive scalar, R14 verbatim)
__global__ __launch_bounds__(256) void qkv_naive(
    const void* __restrict__ nf, const int* __restrict__ cai,
    const void* __restrict__ Wq, const void* __restrict__ Wk, const void* __restrict__ Wv,
    const void* __restrict__ bq, const void* __restrict__ bk, const void* __restrict__ bv,
    void* __restrict__ qf, void* __restrict__ kf, void* __restrict__ vf,
    const int* __restrict__ flag, int qkvf32)
{
    const int r = blockIdx.x, tid = threadIdx.x;
    bool f32 = *flag != 0;
    __shared__ float xs[H_];
    size_t s = (size_t)cai[r] * H_;
    for (int c = tid; c < H_; c += 256) xs[c] = loadf(nf, s + c, f32);
    __syncthreads();
    for (int n = tid; n < 3*H_; n += 256) {
        int mat = n >> 9, col = n & 511;
        const void* W = (mat==0) ? Wq : (mat==1) ? Wk : Wv;
        float acc = 0.f;
        for (int k = 0; k < H_; k++) acc += xs[k] * loadf(W, (size_t)k*H_ + col, f32);
        const void* bias = (mat==0) ? bq : (mat==1) ? bk : bv;
        acc += loadf(bias, col, f32);
        void* dst = (mat==0) ? qf : (mat==1) ? kf : vf;
        if (qkvf32) ((float*)dst)[(size_t)r*H_ + col] = acc;
        else        ((unsigned short*)dst)[(size_t)r*H_ + col] = f2bf(acc);
    }
}

static __device__ __forceinline__ float loadqkv(const void* p, size_t i, int f32m) {
    return f32m ? ((const float*)p)[i] : bf2f(((const unsigned short*)p)[i]);
}

// ---------------------------------------------------------------- tiled attention
// Block = 16 queries x 1 head. Single-pass UNNORMALIZED softmax (|logit|<=~65,
// exp<=1.7e28, den<=3.4e31 — fp32-safe; clamp+finite guards kept). q/k/v come
// from our own qkv_naive (sanitized at source) -> finite by construction.
__global__ __launch_bounds__(256) void attn_tile(
    const void* __restrict__ qf, const void* __restrict__ kf, const void* __restrict__ vf,
    const float* __restrict__ ca, const float* __restrict__ cb,
    const float* __restrict__ fr, const float* __restrict__ maskf,
    float* __restrict__ fa, int qkvf32)
{
    __shared__ __align__(16) float Qs[QT][132];
    __shared__ __align__(16) float Ks[KTL][132];
    __shared__ __align__(16) float Vs[KTL][132];
    __shared__ float Ash[QT][KTL+4];
    __shared__ float caS[KTL][4];
    __shared__ float cbS[QT][3];
    __shared__ float maskQ[QT];
    __shared__ float red[QT][16][4];
    __shared__ float invden[QT];
    const int tid = threadIdx.x;
    const int qbase = blockIdx.x * QT;
    const int h = blockIdx.y;
    // stage Q tile: 16x128 floats
    for (int i = tid; i < QT*32; i += 256) {
        int q = i >> 5, d4 = i & 31;
        size_t base = (size_t)(qbase+q)*H_ + h*HD_ + d4*4;
        if (qkvf32) {
            *(f32x4*)&Qs[q][d4*4] = *(const f32x4*)((const float*)qf + base);
        } else {
            const unsigned short* qb = (const unsigned short*)qf;
            Qs[q][d4*4+0] = bf2f(qb[base+0]); Qs[q][d4*4+1] = bf2f(qb[base+1]);
            Qs[q][d4*4+2] = bf2f(qb[base+2]); Qs[q][d4*4+3] = bf2f(qb[base+3]);
        }
    }
    if (tid < QT) {
        cbS[tid][0] = cb[(qbase+tid)*3+0];
        cbS[tid][1] = cb[(qbase+tid)*3+1];
        cbS[tid][2] = cb[(qbase+tid)*3+2];
        maskQ[tid] = maskf[qbase+tid];
    }
    const int qa = tid & 15, kg = tid >> 4;    // Phase A: (query, key-pair group)
    const int q2 = tid >> 4, ds = tid & 15;    // Phase B: (query, d-slice)
    float pden=0.f, pax=0.f, pay=0.f, paz=0.f;
    float o[8] = {};
    for (int kt = 0; kt < R_/KTL; kt++) {
        const int kb = kt * KTL;
        __syncthreads();   // prior iter's LDS reads done (iter0: Qs/cbS visible)
        for (int i = tid; i < KTL*32; i += 256) {
            int k = i >> 5, d4 = i & 31;
            size_t base = (size_t)(kb+k)*H_ + h*HD_ + d4*4;
            if (qkvf32) {
                *(f32x4*)&Ks[k][d4*4] = *(const f32x4*)((const float*)kf + base);
                *(f32x4*)&Vs[k][d4*4] = *(const f32x4*)((const float*)vf + base);
            } else {
                const unsigned short* kbp = (const unsigned short*)kf;
                const unsigned short* vbp = (const unsigned short*)vf;
                #pragma unroll
                for (int e = 0; e < 4; e++) {
                    Ks[k][d4*4+e] = bf2f(kbp[base+e]);
                    Vs[k][d4*4+e] = bf2f(vbp[base+e]);
                }
            }
        }
        if (tid < KTL) {
            caS[tid][0] = ca[(kb+tid)*3+0];
            caS[tid][1] = ca[(kb+tid)*3+1];
            caS[tid][2] = ca[(kb+tid)*3+2];
            caS[tid][3] = maskf[kb+tid];
        }
        __syncthreads();
        // Phase A: two keys per thread
        const int k0 = kg*2, k1 = kg*2 + 1;
        float dot0 = 0.f, dot1 = 0.f;
        for (int d4 = 0; d4 < 32; d4++) {
            f32x4 qq = *(const f32x4*)&Qs[qa][d4*4];
            f32x4 kv0 = *(const f32x4*)&Ks[k0][d4*4];
            f32x4 kv1 = *(const f32x4*)&Ks[k1][d4*4];
            dot0 += qq[0]*kv0[0] + qq[1]*kv0[1] + qq[2]*kv0[2] + qq[3]*kv0[3];
            dot1 += qq[0]*kv1[0] + qq[1]*kv1[1] + qq[2]*kv1[2] + qq[3]*kv1[3];
        }
        float mq = (maskQ[qa] > 0.f) ? 1.f : 0.f;
        float a0 = __expf(fminf(dot0, 75.f)) * caS[k0][3] * mq;
        float a1 = __expf(fminf(dot1, 75.f)) * caS[k1][3] * mq;
        if (!(a0 < 3.0e38f)) a0 = 0.f;
        if (!(a1 < 3.0e38f)) a1 = 0.f;
        pden += a0 + a1;
        pax += a0*caS[k0][0] + a1*caS[k1][0];
        pay += a0*caS[k0][1] + a1*caS[k1][1];
        paz += a0*caS[k0][2] + a1*caS[k1][2];
        Ash[qa][k0] = a0;
        Ash[qa][k1] = a1;
        __syncthreads();
        // Phase B: o += alpha @ V
        for (int k = 0; k < KTL; k++) {
            float a = Ash[q2][k];
            f32x4 v0 = *(const f32x4*)&Vs[k][ds*8];
            f32x4 v1 = *(const f32x4*)&Vs[k][ds*8 + 4];
            o[0] += a*v0[0]; o[1] += a*v0[1]; o[2] += a*v0[2]; o[3] += a*v0[3];
            o[4] += a*v1[0]; o[5] += a*v1[1]; o[6] += a*v1[2]; o[7] += a*v1[3];
        }
    }
    red[qa][kg][0] = pden; red[qa][kg][1] = pax;
    red[qa][kg][2] = pay;  red[qa][kg][3] = paz;
    __syncthreads();
    if (tid < QT) {
        float den=0.f, ax=0.f, ay=0.f, az=0.f;
        for (int g = 0; g < 16; g++) {
            den += red[tid][g][0]; ax += red[tid][g][1];
            ay  += red[tid][g][2]; az += red[tid][g][3];
        }
        float inv = (den > 0.f) ? 1.f/den : 0.f;
        invden[tid] = inv;
        float live = (den > 0.f) ? 1.f : 0.f;
        int qg = qbase + tid;
        float b0 = cbS[tid][0]*live - ax*inv;
        float b1 = cbS[tid][1]*live - ay*inv;
        float b2 = cbS[tid][2]*live - az*inv;
        float dist = sqrtf(b0*b0 + b1*b1 + b2*b2);
        const float* F = fr + (size_t)qg*9;
        float p0 = F[0]*b0 + F[1]*b1 + F[2]*b2;
        float p1 = F[3]*b0 + F[4]*b1 + F[5]*b2;
        float p2 = F[6]*b0 + F[7]*b1 + F[8]*b2;
        float pn = sqrtf(p0*p0 + p1*p1 + p2*p2) + 1e-10f;
        size_t rb = (size_t)qg * FA_LD;
        fa[rb + 512 + h*3 + 0] = p0;
        fa[rb + 512 + h*3 + 1] = p1;
        fa[rb + 512 + h*3 + 2] = p2;
        fa[rb + 524 + h]       = dist;
        fa[rb + 528 + h*3 + 0] = p0/pn;
        fa[rb + 528 + h*3 + 1] = p1/pn;
        fa[rb + 528 + h*3 + 2] = p2/pn;
        if (h == 0) { fa[rb+540]=0.f; fa[rb+541]=0.f; fa[rb+542]=0.f; fa[rb+543]=0.f; }
    }
    __syncthreads();
    {   // feat_node (divide by den at the end)
        float inv = invden[q2];
        size_t rowb = (size_t)(qbase+q2)*FA_LD + h*HD_;
        #pragma unroll
        for (int j = 0; j < 8; j++)
            fa[rowb + ds*8 + j] = o[j] * inv;
    }
}

// ---------------------------------------------------------------- Wo (naive scalar, R14 verbatim)
__global__ __launch_bounds__(256) void wo_naive(
    const float* __restrict__ fa, const void* __restrict__ Wo,
    const void* __restrict__ bo, float* __restrict__ Y,
    const int* __restrict__ flag)
{
    const int r = blockIdx.x, tid = threadIdx.x;
    bool f32 = *flag != 0;
    __shared__ float fs[FA_LD];
    for (int c = tid; c < FA_LD; c += 256) fs[c] = fa[(size_t)r*FA_LD + c];
    __syncthreads();
    for (int n = tid; n < H_; n += 256) {
        float acc = 0.f;
        for (int k = 0; k < 540; k++) acc += fs[k] * loadf(Wo, (size_t)k*H_ + n, f32);
        Y[(size_t)r*H_ + n] = acc + loadf(bo, n, f32);
    }
}

// ---------------------------------------------------------------- relu+LN1+mask+res+LN2 (R14 verbatim)
__global__ __launch_bounds__(256) void final_ln(
    const float* __restrict__ Y, const void* __restrict__ nf,
    const int* __restrict__ cai, const float* __restrict__ maskf,
    const void* __restrict__ g1, const void* __restrict__ b1,
    const void* __restrict__ g2, const void* __restrict__ b2,
    void* __restrict__ out, const int* __restrict__ flag)
{
    const int tid = threadIdx.x, lane = tid & 63, wave = tid >> 6;
    const int r = blockIdx.x * 4 + wave;
    bool f32 = *flag != 0;
    const float mk = maskf[r];
    const size_t xrow = (size_t)cai[r] * H_;
    float y[8], s1 = 0.f, s2 = 0.f;
    #pragma unroll
    for (int i = 0; i < 8; i++) {
        int c = lane + i*64;
        float v = fmaxf(Y[(size_t)r*H_ + c], 0.f);
        y[i] = v; s1 += v; s2 += v*v;
    }
    #pragma unroll
    for (int off = 32; off; off >>= 1) { s1 += __shfl_xor(s1, off); s2 += __shfl_xor(s2, off); }
    float mu = s1 * (1.f/H_);
    float var = s2 * (1.f/H_) - mu*mu;
    float rstd = rsqrtf(fmaxf(var, 0.f) + 1e-5f);
    float t[8], u1 = 0.f, u2 = 0.f;
    #pragma unroll
    for (int i = 0; i < 8; i++) {
        int c = lane + i*64;
        float hh = (y[i]-mu)*rstd*loadf(g1, c, f32) + loadf(b1, c, f32);
        hh *= mk;
        float tv = loadf(nf, xrow + c, f32) + hh;
        t[i] = tv; u1 += tv; u2 += tv*tv;
    }
    #pragma unroll
    for (int off = 32; off; off >>= 1) { u1 += __shfl_xor(u1, off); u2 += __shfl_xor(u2, off); }
    float mu2 = u1 * (1.f/H_);
    float var2 = u2 * (1.f/H_) - mu2*mu2;
    float rstd2 = rsqrtf(fmaxf(var2, 0.f) + 1e-5f);
    #pragma unroll
    for (int i = 0; i < 8; i++) {
        int c = lane + i*64;
        float ov = (t[i]-mu2)*rstd2*loadf(g2, c, f32) + loadf(b2, c, f32);
        if (f32) ((float*)out)[(size_t)r*H_ + c] = ov;
        else ((unsigned short*)out)[(size_t)r*H_ + c] = f2bf(ov);
    }
}

// ---------------------------------------------------------------- launch
extern "C" void kernel_launch(void* const* d_in, const int* in_sizes, int n_in,
                              void* d_out, int out_size, void* d_ws, size_t ws_size,
                              hipStream_t stream)
{
    // ---- host-side signature verification (debug channel via out[0]) ----
    static const int expected[16] = {
        8388608, 49152, 262144, 512, 262144, 512, 262144, 512,
        276480, 512, 512, 512, 512, 512, 16384, 16384
    };
    if (n_in != 16) {
        diag<<<dim3(1), dim3(64), 0, stream>>>((unsigned short*)d_out, 1000.f + n_in);
        return;
    }
    for (int i = 0; i < 16; i++) {
        if (in_sizes[i] != expected[i]) {
            diag<<<dim3(1), dim3(64), 0, stream>>>((unsigned short*)d_out, 2000.f + 10.f*i);
            return;
        }
    }
    const size_t smallEnd = 1u << 20;               // 1MB for small buffers
    const size_t qkvF32Bytes = (size_t)R_*H_*4;     // 4MB each
    const size_t qkvBF16Bytes = (size_t)R_*H_*2;    // 2MB each
    const size_t faBytes = (size_t)R_*FA_LD*4;      // 4.46MB
    const size_t needF32  = smallEnd + 3*qkvF32Bytes + faBytes;   // ~18.1MB
    const size_t needBF16 = smallEnd + 3*qkvBF16Bytes + faBytes;  // ~11.8MB
    if (ws_size < needBF16) {
        diag<<<dim3(1), dim3(64), 0, stream>>>((unsigned short*)d_out, 3000.f);
        return;
    }
    const int qkvf32 = (ws_size >= needF32) ? 1 : 0;
    const size_t qkvBytes = qkvf32 ? qkvF32Bytes : qkvBF16Bytes;

    const void* nf  = d_in[0];
    const void* pos = d_in[1];
    const void* Wq  = d_in[2];  const void* bq = d_in[3];
    const void* Wk  = d_in[4];  const void* bk = d_in[5];
    const void* Wv  = d_in[6];  const void* bv = d_in[7];
    const void* Wo  = d_in[8];  const void* bo = d_in[9];
    const void* g1  = d_in[10]; const void* b1 = d_in[11];
    const void* g2  = d_in[12]; const void* b2 = d_in[13];
    const int* atype = (const int*)d_in[14];

    char* ws = (char*)d_ws;
    int*   flag  = (int*)  (ws + 0);
    int*   cai   = (int*)  (ws + 1024);
    float* ca    = (float*)(ws + 9216);
    float* cb    = (float*)(ws + 33792);
    float* fr    = (float*)(ws + 58368);
    float* maskf = (float*)(ws + 132096);
    void*  qf = ws + smallEnd;
    void*  kf = ws + smallEnd + qkvBytes;
    void*  vf = ws + smallEnd + 2*qkvBytes;
    float* fa = (float*)(ws + smallEnd + 3*qkvBytes);
    float* Y  = (float*)qf;   // aliases qf(+kf) — both dead after attn

    detect_dtype<<<dim3(1), dim3(256), 0, stream>>>((const unsigned short*)nf, flag);
    gather_frames<<<dim3(8), dim3(256), 0, stream>>>(pos, atype, flag, cai, ca, cb, fr, maskf);
    qkv_naive<<<dim3(R_), dim3(256), 0, stream>>>(nf, cai, Wq, Wk, Wv, bq, bk, bv,
                                                  qf, kf, vf, flag, qkvf32);
    attn_tile<<<dim3(R_/QT, HEADS_), dim3(256), 0, stream>>>(qf, kf, vf, ca, cb, fr, maskf,
                                                             fa, qkvf32);
    wo_naive<<<dim3(R_), dim3(256), 0, stream>>>(fa, Wo, bo, Y, flag);
    final_ln<<<dim3(512), dim3(256), 0, stream>>>(Y, nf, cai, maskf, g1, b1, g2, b2,
                                                  d_out, flag);
}

// Round 16
// 655.090 us; speedup vs baseline: 10.9705x; 1.3874x over previous
//
#include <hip/hip_runtime.h>
#include <hip/hip_bf16.h>
#include <stdint.h>

// GeometricGNN on MI355X. R=2048, APR=8, H=512, HEADS=4, HD=128, SD=28.
// Round 16: R15 (passing, 909us) with qkv_naive and wo_naive replaced by
// register-blocked LDS-tiled VALU GEMMs (64x64 tile, 4x4 acc/thread,
// k-ascending accumulation -> BIT-IDENTICAL numerics to R15).
// Sanitized-loadf invariant + flag machinery + ws layout verbatim.

#define R_ 2048
#define APR_ 8
#define H_ 512
#define HEADS_ 4
#define HD_ 128
#define FA_LD 544
#define QT 16
#define KTL 32

typedef __attribute__((ext_vector_type(4))) float f32x4;

static __device__ __forceinline__ float bf2f(unsigned short u) {
    union { unsigned int i; float f; } c; c.i = ((unsigned int)u) << 16; return c.f;
}
static __device__ __forceinline__ unsigned short f2bf(float f) {
    union { float f; unsigned int i; } c; c.f = f;
    unsigned int r = c.i + 0x7fffu + ((c.i >> 16) & 1u);   // RNE
    return (unsigned short)(r >> 16);
}
// flag-aware, sanitized load of logical element i of a float input array
static __device__ __forceinline__ float loadf(const void* p, size_t i, bool f32) {
    float v = f32 ? ((const float*)p)[i] : bf2f(((const unsigned short*)p)[i]);
    return (v == v && fabsf(v) < 1e30f) ? v : 0.f;
}

// ---------------------------------------------------------------- diag
__global__ void diag(unsigned short* out, float val) {
    if (threadIdx.x == 0 && blockIdx.x == 0) out[0] = f2bf(val);
}

// ---------------------------------------------------------------- dtype detect (d_in[0])
__global__ void detect_dtype(const unsigned short* __restrict__ nf, int* flag) {
    __shared__ int bad;
    if (threadIdx.x == 0) bad = 0;
    __syncthreads();
    int cnt = 0;
    for (int i = threadIdx.x; i < 8192; i += 256) {
        unsigned e = (nf[i] >> 7) & 0xFFu;
        if (e >= 0xC0u) cnt++;
    }
    atomicAdd(&bad, cnt);
    __syncthreads();
    if (threadIdx.x == 0) *flag = (bad > 16) ? 1 : 0;
}

// ---------------------------------------------------------------- gather + frames (R15 verbatim)
__global__ void gather_frames(const void* __restrict__ pos,
                              const int* __restrict__ atype,
                              const int* __restrict__ flag,
                              int* __restrict__ cai, float* __restrict__ ca,
                              float* __restrict__ cb, float* __restrict__ fr,
                              float* __restrict__ maskf)
{
    int r = blockIdx.x * blockDim.x + threadIdx.x;
    if (r >= R_) return;
    bool f32 = *flag != 0;
    int base = r * APR_;
    float caP[3] = {0,0,0}, cbP[3] = {0,0,0};
    int idx = base; bool h0=false, h1=false, h2=false;
    for (int a = 0; a < APR_; a++) {
        int t = atype[base + a];
        if (t == 0) h0 = true;
        if (t == 2) h2 = true;
        if (t == 1) { h1 = true; idx = base + a;
            for (int j = 0; j < 3; j++) caP[j] += loadf(pos, (size_t)(base+a)*3 + j, f32); }
        if (t == 4) {
            for (int j = 0; j < 3; j++) cbP[j] += loadf(pos, (size_t)(base+a)*3 + j, f32); }
    }
    float s = fabsf(cbP[0]) + fabsf(cbP[1]) + fabsf(cbP[2]);
    if (s < 1e-6f) { cbP[0]=caP[0]; cbP[1]=caP[1]; cbP[2]=caP[2]; }
    float e1[3] = { cbP[0]-caP[0], cbP[1]-caP[1], cbP[2]-caP[2] };
    float n1 = sqrtf(e1[0]*e1[0] + e1[1]*e1[1] + e1[2]*e1[2]);
    float e1u[3] = { e1[0], e1[1], e1[2] };
    if (n1 > 1e-6f) { float iv = 1.f / fmaxf(n1, 1e-6f); e1u[0]*=iv; e1u[1]*=iv; e1u[2]*=iv; }
    float e2a[3] = { e1u[1], -e1u[0], 0.f };
    float n2a = sqrtf(e2a[0]*e2a[0] + e2a[1]*e2a[1]);
    float e2b[3] = { -e1u[2], 0.f, e1u[0] };
    float n2b = sqrtf(e2b[0]*e2b[0] + e2b[2]*e2b[2]);
    bool useb = n2a < 1e-6f;
    float e2[3] = { useb?e2b[0]:e2a[0], useb?e2b[1]:e2a[1], useb?e2b[2]:e2a[2] };
    float n2 = useb ? n2b : n2a;
    float iv2 = 1.f / fmaxf(n2, 1e-6f);
    float e2u[3] = { e2[0]*iv2, e2[1]*iv2, e2[2]*iv2 };
    float e3[3] = { e1u[1]*e2u[2]-e1u[2]*e2u[1],
                    e1u[2]*e2u[0]-e1u[0]*e2u[2],
                    e1u[0]*e2u[1]-e1u[1]*e2u[0] };
    bool ok = (r < R_-1) && (n1 > 1e-6f) && (n2 > 1e-6f);
    float F[9];
    if (ok) { F[0]=e1u[0]; F[1]=e2u[0]; F[2]=e3[0];
              F[3]=e1u[1]; F[4]=e2u[1]; F[5]=e3[1];
              F[6]=e1u[2]; F[7]=e2u[2]; F[8]=e3[2]; }
    else    { F[0]=1;F[1]=0;F[2]=0; F[3]=0;F[4]=1;F[5]=0; F[6]=0;F[7]=0;F[8]=1; }
    cai[r] = idx;
    for (int j = 0; j < 3; j++) { ca[r*3+j] = caP[j]; cb[r*3+j] = cbP[j]; }
    for (int j = 0; j < 9; j++) fr[r*9+j] = F[j];
    maskf[r] = (h0 && h1 && h2) ? 1.f : 0.f;
}

// ---------------------------------------------------------------- QKV tiled GEMM (VALU, 4x4 regs)
// C[m,n] = sum_k X[m,k]*W[k,n] + b[n], k ascending 0..511 -> bit-identical to
// the scalar version. 64x64 tile, K in 32-slabs via LDS.
__global__ __launch_bounds__(256) void qkv_tile(
    const void* __restrict__ nf, const int* __restrict__ cai,
    const void* __restrict__ Wq, const void* __restrict__ Wk, const void* __restrict__ Wv,
    const void* __restrict__ bq, const void* __restrict__ bk, const void* __restrict__ bv,
    void* __restrict__ qf, void* __restrict__ kf, void* __restrict__ vf,
    const int* __restrict__ flag, int qkvf32)
{
    __shared__ __align__(16) float Xs[32][68];   // [k][m]
    __shared__ __align__(16) float Wsh[32][68];  // [k][n]
    __shared__ int cais[64];
    const int tid = threadIdx.x;
    const int mbase = blockIdx.x * 64;
    const int nblk  = blockIdx.y * 64;           // 0..1535
    const int mat   = nblk >> 9;
    const int ncol0 = nblk & 511;
    bool f32 = *flag != 0;
    const void* W = (mat==0) ? Wq : (mat==1) ? Wk : Wv;
    const int tm = tid >> 4, tn = tid & 15;
    float acc[4][4] = {};
    if (tid < 64) cais[tid] = cai[mbase + tid];
    for (int kt = 0; kt < 16; kt++) {
        const int k0 = kt * 32;
        __syncthreads();   // prior iter reads done; iter0: cais visible
        for (int i = tid; i < 64*32; i += 256) {
            int m = i >> 5, kk = i & 31;
            Xs[kk][m] = loadf(nf, (size_t)cais[m]*H_ + k0 + kk, f32);
        }
        for (int i = tid; i < 32*64; i += 256) {
            int kk = i >> 6, nn = i & 63;
            Wsh[kk][nn] = loadf(W, (size_t)(k0+kk)*H_ + ncol0 + nn, f32);
        }
        __syncthreads();
        for (int k = 0; k < 32; k++) {
            f32x4 a = *(const f32x4*)&Xs[k][tm*4];
            f32x4 b = *(const f32x4*)&Wsh[k][tn*4];
            #pragma unroll
            for (int i = 0; i < 4; i++)
                #pragma unroll
                for (int j = 0; j < 4; j++)
                    acc[i][j] += a[i] * b[j];
        }
    }
    const void* bias = (mat==0) ? bq : (mat==1) ? bk : bv;
    void* dst = (mat==0) ? qf : (mat==1) ? kf : vf;
    #pragma unroll
    for (int i = 0; i < 4; i++) {
        int m = mbase + tm*4 + i;
        #pragma unroll
        for (int j = 0; j < 4; j++) {
            int col = ncol0 + tn*4 + j;
            float val = acc[i][j] + loadf(bias, col, f32);
            if (qkvf32) ((float*)dst)[(size_t)m*H_ + col] = val;
            else        ((unsigned short*)dst)[(size_t)m*H_ + col] = f2bf(val);
        }
    }
}

// ---------------------------------------------------------------- tiled attention (R15 verbatim)
__global__ __launch_bounds__(256) void attn_tile(
    const void* __restrict__ qf, const void* __restrict__ kf, const void* __restrict__ vf,
    const float* __restrict__ ca, const float* __restrict__ cb,
    const float* __restrict__ fr, const float* __restrict__ maskf,
    float* __restrict__ fa, int qkvf32)
{
    __shared__ __align__(16) float Qs[QT][132];
    __shared__ __align__(16) float Ks[KTL][132];
    __shared__ __align__(16) float Vs[KTL][132];
    __shared__ float Ash[QT][KTL+4];
    __shared__ float caS[KTL][4];
    __shared__ float cbS[QT][3];
    __shared__ float maskQ[QT];
    __shared__ float red[QT][16][4];
    __shared__ float invden[QT];
    const int tid = threadIdx.x;
    const int qbase = blockIdx.x * QT;
    const int h = blockIdx.y;
    for (int i = tid; i < QT*32; i += 256) {
        int q = i >> 5, d4 = i & 31;
        size_t base = (size_t)(qbase+q)*H_ + h*HD_ + d4*4;
        if (qkvf32) {
            *(f32x4*)&Qs[q][d4*4] = *(const f32x4*)((const float*)qf + base);
        } else {
            const unsigned short* qb = (const unsigned short*)qf;
            Qs[q][d4*4+0] = bf2f(qb[base+0]); Qs[q][d4*4+1] = bf2f(qb[base+1]);
            Qs[q][d4*4+2] = bf2f(qb[base+2]); Qs[q][d4*4+3] = bf2f(qb[base+3]);
        }
    }
    if (tid < QT) {
        cbS[tid][0] = cb[(qbase+tid)*3+0];
        cbS[tid][1] = cb[(qbase+tid)*3+1];
        cbS[tid][2] = cb[(qbase+tid)*3+2];
        maskQ[tid] = maskf[qbase+tid];
    }
    const int qa = tid & 15, kg = tid >> 4;
    const int q2 = tid >> 4, ds = tid & 15;
    float pden=0.f, pax=0.f, pay=0.f, paz=0.f;
    float o[8] = {};
    for (int kt = 0; kt < R_/KTL; kt++) {
        const int kb = kt * KTL;
        __syncthreads();
        for (int i = tid; i < KTL*32; i += 256) {
            int k = i >> 5, d4 = i & 31;
            size_t base = (size_t)(kb+k)*H_ + h*HD_ + d4*4;
            if (qkvf32) {
                *(f32x4*)&Ks[k][d4*4] = *(const f32x4*)((const float*)kf + base);
                *(f32x4*)&Vs[k][d4*4] = *(const f32x4*)((const float*)vf + base);
            } else {
                const unsigned short* kbp = (const unsigned short*)kf;
                const unsigned short* vbp = (const unsigned short*)vf;
                #pragma unroll
                for (int e = 0; e < 4; e++) {
                    Ks[k][d4*4+e] = bf2f(kbp[base+e]);
                    Vs[k][d4*4+e] = bf2f(vbp[base+e]);
                }
            }
        }
        if (tid < KTL) {
            caS[tid][0] = ca[(kb+tid)*3+0];
            caS[tid][1] = ca[(kb+tid)*3+1];
            caS[tid][2] = ca[(kb+tid)*3+2];
            caS[tid][3] = maskf[kb+tid];
        }
        __syncthreads();
        const int k0 = kg*2, k1 = kg*2 + 1;
        float dot0 = 0.f, dot1 = 0.f;
        for (int d4 = 0; d4 < 32; d4++) {
            f32x4 qq = *(const f32x4*)&Qs[qa][d4*4];
            f32x4 kv0 = *(const f32x4*)&Ks[k0][d4*4];
            f32x4 kv1 = *(const f32x4*)&Ks[k1][d4*4];
            dot0 += qq[0]*kv0[0] + qq[1]*kv0[1] + qq[2]*kv0[2] + qq[3]*kv0[3];
            dot1 += qq[0]*kv1[0] + qq[1]*kv1[1] + qq[2]*kv1[2] + qq[3]*kv1[3];
        }
        float mq = (maskQ[qa] > 0.f) ? 1.f : 0.f;
        float a0 = __expf(fminf(dot0, 75.f)) * caS[k0][3] * mq;
        float a1 = __expf(fminf(dot1, 75.f)) * caS[k1][3] * mq;
        if (!(a0 < 3.0e38f)) a0 = 0.f;
        if (!(a1 < 3.0e38f)) a1 = 0.f;
        pden += a0 + a1;
        pax += a0*caS[k0][0] + a1*caS[k1][0];
        pay += a0*caS[k0][1] + a1*caS[k1][1];
        paz += a0*caS[k0][2] + a1*caS[k1][2];
        Ash[qa][k0] = a0;
        Ash[qa][k1] = a1;
        __syncthreads();
        for (int k = 0; k < KTL; k++) {
            float a = Ash[q2][k];
            f32x4 v0 = *(const f32x4*)&Vs[k][ds*8];
            f32x4 v1 = *(const f32x4*)&Vs[k][ds*8 + 4];
            o[0] += a*v0[0]; o[1] += a*v0[1]; o[2] += a*v0[2]; o[3] += a*v0[3];
            o[4] += a*v1[0]; o[5] += a*v1[1]; o[6] += a*v1[2]; o[7] += a*v1[3];
        }
    }
    red[qa][kg][0] = pden; red[qa][kg][1] = pax;
    red[qa][kg][2] = pay;  red[qa][kg][3] = paz;
    __syncthreads();
    if (tid < QT) {
        float den=0.f, ax=0.f, ay=0.f, az=0.f;
        for (int g = 0; g < 16; g++) {
            den += red[tid][g][0]; ax += red[tid][g][1];
            ay  += red[tid][g][2]; az += red[tid][g][3];
        }
        float inv = (den > 0.f) ? 1.f/den : 0.f;
        invden[tid] = inv;
        float live = (den > 0.f) ? 1.f : 0.f;
        int qg = qbase + tid;
        float b0 = cbS[tid][0]*live - ax*inv;
        float b1 = cbS[tid][1]*live - ay*inv;
        float b2 = cbS[tid][2]*live - az*inv;
        float dist = sqrtf(b0*b0 + b1*b1 + b2*b2);
        const float* F = fr + (size_t)qg*9;
        float p0 = F[0]*b0 + F[1]*b1 + F[2]*b2;
        float p1 = F[3]*b0 + F[4]*b1 + F[5]*b2;
        float p2 = F[6]*b0 + F[7]*b1 + F[8]*b2;
        float pn = sqrtf(p0*p0 + p1*p1 + p2*p2) + 1e-10f;
        size_t rb = (size_t)qg * FA_LD;
        fa[rb + 512 + h*3 + 0] = p0;
        fa[rb + 512 + h*3 + 1] = p1;
        fa[rb + 512 + h*3 + 2] = p2;
        fa[rb + 524 + h]       = dist;
        fa[rb + 528 + h*3 + 0] = p0/pn;
        fa[rb + 528 + h*3 + 1] = p1/pn;
        fa[rb + 528 + h*3 + 2] = p2/pn;
        if (h == 0) { fa[rb+540]=0.f; fa[rb+541]=0.f; fa[rb+542]=0.f; fa[rb+543]=0.f; }
    }
    __syncthreads();
    {
        float inv = invden[q2];
        size_t rowb = (size_t)(qbase+q2)*FA_LD + h*HD_;
        #pragma unroll
        for (int j = 0; j < 8; j++)
            fa[rowb + ds*8 + j] = o[j] * inv;
    }
}

// ---------------------------------------------------------------- Wo tiled GEMM (VALU, 4x4 regs)
// K runs 0..543 (rows 540..543 read as 0; fa[.,540..543] are zeroed) —
// contribution exactly 0, accumulation order matches wo_naive.
__global__ __launch_bounds__(256) void wo_tile(
    const float* __restrict__ fa, const void* __restrict__ Wo,
    const void* __restrict__ bo, float* __restrict__ Y,
    const int* __restrict__ flag)
{
    __shared__ __align__(16) float Xs[32][68];   // [k][m]
    __shared__ __align__(16) float Wsh[32][68];  // [k][n]
    const int tid = threadIdx.x;
    const int mbase = blockIdx.x * 64;
    const int nbase = blockIdx.y * 64;
    bool f32 = *flag != 0;
    const int tm = tid >> 4, tn = tid & 15;
    float acc[4][4] = {};
    for (int kt = 0; kt < 17; kt++) {
        const int k0 = kt * 32;
        __syncthreads();
        for (int i = tid; i < 64*32; i += 256) {
            int m = i >> 5, kk = i & 31;
            Xs[kk][m] = fa[(size_t)(mbase+m)*FA_LD + k0 + kk];
        }
        for (int i = tid; i < 32*64; i += 256) {
            int kk = i >> 6, nn = i & 63;
            int krow = k0 + kk;
            Wsh[kk][nn] = (krow < 540) ? loadf(Wo, (size_t)krow*H_ + nbase + nn, f32) : 0.f;
        }
        __syncthreads();
        for (int k = 0; k < 32; k++) {
            f32x4 a = *(const f32x4*)&Xs[k][tm*4];
            f32x4 b = *(const f32x4*)&Wsh[k][tn*4];
            #pragma unroll
            for (int i = 0; i < 4; i++)
                #pragma unroll
                for (int j = 0; j < 4; j++)
                    acc[i][j] += a[i] * b[j];
        }
    }
    #pragma unroll
    for (int i = 0; i < 4; i++) {
        int m = mbase + tm*4 + i;
        #pragma unroll
        for (int j = 0; j < 4; j++) {
            int n = nbase + tn*4 + j;
            Y[(size_t)m*H_ + n] = acc[i][j] + loadf(bo, n, f32);
        }
    }
}

// ---------------------------------------------------------------- relu+LN1+mask+res+LN2 (R15 verbatim)
__global__ __launch_bounds__(256) void final_ln(
    const float* __restrict__ Y, const void* __restrict__ nf,
    const int* __restrict__ cai, const float* __restrict__ maskf,
    const void* __restrict__ g1, const void* __restrict__ b1,
    const void* __restrict__ g2, const void* __restrict__ b2,
    void* __restrict__ out, const int* __restrict__ flag)
{
    const int tid = threadIdx.x, lane = tid & 63, wave = tid >> 6;
    const int r = blockIdx.x * 4 + wave;
    bool f32 = *flag != 0;
    const float mk = maskf[r];
    const size_t xrow = (size_t)cai[r] * H_;
    float y[8], s1 = 0.f, s2 = 0.f;
    #pragma unroll
    for (int i = 0; i < 8; i++) {
        int c = lane + i*64;
        float v = fmaxf(Y[(size_t)r*H_ + c], 0.f);
        y[i] = v; s1 += v; s2 += v*v;
    }
    #pragma unroll
    for (int off = 32; off; off >>= 1) { s1 += __shfl_xor(s1, off); s2 += __shfl_xor(s2, off); }
    float mu = s1 * (1.f/H_);
    float var = s2 * (1.f/H_) - mu*mu;
    float rstd = rsqrtf(fmaxf(var, 0.f) + 1e-5f);
    float t[8], u1 = 0.f, u2 = 0.f;
    #pragma unroll
    for (int i = 0; i < 8; i++) {
        int c = lane + i*64;
        float hh = (y[i]-mu)*rstd*loadf(g1, c, f32) + loadf(b1, c, f32);
        hh *= mk;
        float tv = loadf(nf, xrow + c, f32) + hh;
        t[i] = tv; u1 += tv; u2 += tv*tv;
    }
    #pragma unroll
    for (int off = 32; off; off >>= 1) { u1 += __shfl_xor(u1, off); u2 += __shfl_xor(u2, off); }
    float mu2 = u1 * (1.f/H_);
    float var2 = u2 * (1.f/H_) - mu2*mu2;
    float rstd2 = rsqrtf(fmaxf(var2, 0.f) + 1e-5f);
    #pragma unroll
    for (int i = 0; i < 8; i++) {
        int c = lane + i*64;
        float ov = (t[i]-mu2)*rstd2*loadf(g2, c, f32) + loadf(b2, c, f32);
        if (f32) ((float*)out)[(size_t)r*H_ + c] = ov;
        else ((unsigned short*)out)[(size_t)r*H_ + c] = f2bf(ov);
    }
}

// ---------------------------------------------------------------- launch
extern "C" void kernel_launch(void* const* d_in, const int* in_sizes, int n_in,
                              void* d_out, int out_size, void* d_ws, size_t ws_size,
                              hipStream_t stream)
{
    static const int expected[16] = {
        8388608, 49152, 262144, 512, 262144, 512, 262144, 512,
        276480, 512, 512, 512, 512, 512, 16384, 16384
    };
    if (n_in != 16) {
        diag<<<dim3(1), dim3(64), 0, stream>>>((unsigned short*)d_out, 1000.f + n_in);
        return;
    }
    for (int i = 0; i < 16; i++) {
        if (in_sizes[i] != expected[i]) {
            diag<<<dim3(1), dim3(64), 0, stream>>>((unsigned short*)d_out, 2000.f + 10.f*i);
            return;
        }
    }
    const size_t smallEnd = 1u << 20;
    const size_t qkvF32Bytes = (size_t)R_*H_*4;
    const size_t qkvBF16Bytes = (size_t)R_*H_*2;
    const size_t faBytes = (size_t)R_*FA_LD*4;
    const size_t needF32  = smallEnd + 3*qkvF32Bytes + faBytes;
    const size_t needBF16 = smallEnd + 3*qkvBF16Bytes + faBytes;
    if (ws_size < needBF16) {
        diag<<<dim3(1), dim3(64), 0, stream>>>((unsigned short*)d_out, 3000.f);
        return;
    }
    const int qkvf32 = (ws_size >= needF32) ? 1 : 0;
    const size_t qkvBytes = qkvf32 ? qkvF32Bytes : qkvBF16Bytes;

    const void* nf  = d_in[0];
    const void* pos = d_in[1];
    const void* Wq  = d_in[2];  const void* bq = d_in[3];
    const void* Wk  = d_in[4];  const void* bk = d_in[5];
    const void* Wv  = d_in[6];  const void* bv = d_in[7];
    const void* Wo  = d_in[8];  const void* bo = d_in[9];
    const void* g1  = d_in[10]; const void* b1 = d_in[11];
    const void* g2  = d_in[12]; const void* b2 = d_in[13];
    const int* atype = (const int*)d_in[14];

    char* ws = (char*)d_ws;
    int*   flag  = (int*)  (ws + 0);
    int*   cai   = (int*)  (ws + 1024);
    float* ca    = (float*)(ws + 9216);
    float* cb    = (float*)(ws + 33792);
    float* fr    = (float*)(ws + 58368);
    float* maskf = (float*)(ws + 132096);
    void*  qf = ws + smallEnd;
    void*  kf = ws + smallEnd + qkvBytes;
    void*  vf = ws + smallEnd + 2*qkvBytes;
    float* fa = (float*)(ws + smallEnd + 3*qkvBytes);
    float* Y  = (float*)qf;   // aliases qf(+kf) — both dead after attn

    detect_dtype<<<dim3(1), dim3(256), 0, stream>>>((const unsigned short*)nf, flag);
    gather_frames<<<dim3(8), dim3(256), 0, stream>>>(pos, atype, flag, cai, ca, cb, fr, maskf);
    qkv_tile<<<dim3(R_/64, 24), dim3(256), 0, stream>>>(nf, cai, Wq, Wk, Wv, bq, bk, bv,
                                                        qf, kf, vf, flag, qkvf32);
    attn_tile<<<dim3(R_/QT, HEADS_), dim3(256), 0, stream>>>(qf, kf, vf, ca, cb, fr, maskf,
                                                             fa, qkvf32);
    wo_tile<<<dim3(R_/64, H_/64), dim3(256), 0, stream>>>(fa, Wo, bo, Y, flag);
    final_ln<<<dim3(512), dim3(256), 0, stream>>>(Y, nf, cai, maskf, g1, b1, g2, b2,
                                                  d_out, flag);
}

// Round 17
// 611.407 us; speedup vs baseline: 11.7543x; 1.0714x over previous
//
#include <hip/hip_runtime.h>
#include <hip/hip_bf16.h>
#include <stdint.h>

// GeometricGNN on MI355X. R=2048, APR=8, H=512, HEADS=4, HD=128, SD=28.
// Round 17: R16 (passing, 655us) with ONLY attn_tile replaced: QT=32, 2x2
// register blocking in Phase A (interleaved q/k pairs for bank-conflict-free
// reads), 4x4 in Phase B via transposed alpha tile. LDS B/FLOP 2.75 -> 1.5.
// Everything else byte-identical to R16.

#define R_ 2048
#define APR_ 8
#define H_ 512
#define HEADS_ 4
#define HD_ 128
#define FA_LD 544
#define QT2 32
#define KT2 32

typedef __attribute__((ext_vector_type(4))) float f32x4;

static __device__ __forceinline__ float bf2f(unsigned short u) {
    union { unsigned int i; float f; } c; c.i = ((unsigned int)u) << 16; return c.f;
}
static __device__ __forceinline__ unsigned short f2bf(float f) {
    union { float f; unsigned int i; } c; c.f = f;
    unsigned int r = c.i + 0x7fffu + ((c.i >> 16) & 1u);   // RNE
    return (unsigned short)(r >> 16);
}
// flag-aware, sanitized load of logical element i of a float input array
static __device__ __forceinline__ float loadf(const void* p, size_t i, bool f32) {
    float v = f32 ? ((const float*)p)[i] : bf2f(((const unsigned short*)p)[i]);
    return (v == v && fabsf(v) < 1e30f) ? v : 0.f;
}

// ---------------------------------------------------------------- diag
__global__ void diag(unsigned short* out, float val) {
    if (threadIdx.x == 0 && blockIdx.x == 0) out[0] = f2bf(val);
}

// ---------------------------------------------------------------- dtype detect (d_in[0])
__global__ void detect_dtype(const unsigned short* __restrict__ nf, int* flag) {
    __shared__ int bad;
    if (threadIdx.x == 0) bad = 0;
    __syncthreads();
    int cnt = 0;
    for (int i = threadIdx.x; i < 8192; i += 256) {
        unsigned e = (nf[i] >> 7) & 0xFFu;
        if (e >= 0xC0u) cnt++;
    }
    atomicAdd(&bad, cnt);
    __syncthreads();
    if (threadIdx.x == 0) *flag = (bad > 16) ? 1 : 0;
}

// ---------------------------------------------------------------- gather + frames (R16 verbatim)
__global__ void gather_frames(const void* __restrict__ pos,
                              const int* __restrict__ atype,
                              const int* __restrict__ flag,
                              int* __restrict__ cai, float* __restrict__ ca,
                              float* __restrict__ cb, float* __restrict__ fr,
                              float* __restrict__ maskf)
{
    int r = blockIdx.x * blockDim.x + threadIdx.x;
    if (r >= R_) return;
    bool f32 = *flag != 0;
    int base = r * APR_;
    float caP[3] = {0,0,0}, cbP[3] = {0,0,0};
    int idx = base; bool h0=false, h1=false, h2=false;
    for (int a = 0; a < APR_; a++) {
        int t = atype[base + a];
        if (t == 0) h0 = true;
        if (t == 2) h2 = true;
        if (t == 1) { h1 = true; idx = base + a;
            for (int j = 0; j < 3; j++) caP[j] += loadf(pos, (size_t)(base+a)*3 + j, f32); }
        if (t == 4) {
            for (int j = 0; j < 3; j++) cbP[j] += loadf(pos, (size_t)(base+a)*3 + j, f32); }
    }
    float s = fabsf(cbP[0]) + fabsf(cbP[1]) + fabsf(cbP[2]);
    if (s < 1e-6f) { cbP[0]=caP[0]; cbP[1]=caP[1]; cbP[2]=caP[2]; }
    float e1[3] = { cbP[0]-caP[0], cbP[1]-caP[1], cbP[2]-caP[2] };
    float n1 = sqrtf(e1[0]*e1[0] + e1[1]*e1[1] + e1[2]*e1[2]);
    float e1u[3] = { e1[0], e1[1], e1[2] };
    if (n1 > 1e-6f) { float iv = 1.f / fmaxf(n1, 1e-6f); e1u[0]*=iv; e1u[1]*=iv; e1u[2]*=iv; }
    float e2a[3] = { e1u[1], -e1u[0], 0.f };
    float n2a = sqrtf(e2a[0]*e2a[0] + e2a[1]*e2a[1]);
    float e2b[3] = { -e1u[2], 0.f, e1u[0] };
    float n2b = sqrtf(e2b[0]*e2b[0] + e2b[2]*e2b[2]);
    bool useb = n2a < 1e-6f;
    float e2[3] = { useb?e2b[0]:e2a[0], useb?e2b[1]:e2a[1], useb?e2b[2]:e2a[2] };
    float n2 = useb ? n2b : n2a;
    float iv2 = 1.f / fmaxf(n2, 1e-6f);
    float e2u[3] = { e2[0]*iv2, e2[1]*iv2, e2[2]*iv2 };
    float e3[3] = { e1u[1]*e2u[2]-e1u[2]*e2u[1],
                    e1u[2]*e2u[0]-e1u[0]*e2u[2],
                    e1u[0]*e2u[1]-e1u[1]*e2u[0] };
    bool ok = (r < R_-1) && (n1 > 1e-6f) && (n2 > 1e-6f);
    float F[9];
    if (ok) { F[0]=e1u[0]; F[1]=e2u[0]; F[2]=e3[0];
              F[3]=e1u[1]; F[4]=e2u[1]; F[5]=e3[1];
              F[6]=e1u[2]; F[7]=e2u[2]; F[8]=e3[2]; }
    else    { F[0]=1;F[1]=0;F[2]=0; F[3]=0;F[4]=1;F[5]=0; F[6]=0;F[7]=0;F[8]=1; }
    cai[r] = idx;
    for (int j = 0; j < 3; j++) { ca[r*3+j] = caP[j]; cb[r*3+j] = cbP[j]; }
    for (int j = 0; j < 9; j++) fr[r*9+j] = F[j];
    maskf[r] = (h0 && h1 && h2) ? 1.f : 0.f;
}

// ---------------------------------------------------------------- QKV tiled GEMM (R16 verbatim)
__global__ __launch_bounds__(256) void qkv_tile(
    const void* __restrict__ nf, const int* __restrict__ cai,
    const void* __restrict__ Wq, const void* __restrict__ Wk, const void* __restrict__ Wv,
    const void* __restrict__ bq, const void* __restrict__ bk, const void* __restrict__ bv,
    void* __restrict__ qf, void* __restrict__ kf, void* __restrict__ vf,
    const int* __restrict__ flag, int qkvf32)
{
    __shared__ __align__(16) float Xs[32][68];   // [k][m]
    __shared__ __align__(16) float Wsh[32][68];  // [k][n]
    __shared__ int cais[64];
    const int tid = threadIdx.x;
    const int mbase = blockIdx.x * 64;
    const int nblk  = blockIdx.y * 64;           // 0..1535
    const int mat   = nblk >> 9;
    const int ncol0 = nblk & 511;
    bool f32 = *flag != 0;
    const void* W = (mat==0) ? Wq : (mat==1) ? Wk : Wv;
    const int tm = tid >> 4, tn = tid & 15;
    float acc[4][4] = {};
    if (tid < 64) cais[tid] = cai[mbase + tid];
    for (int kt = 0; kt < 16; kt++) {
        const int k0 = kt * 32;
        __syncthreads();   // prior iter reads done; iter0: cais visible
        for (int i = tid; i < 64*32; i += 256) {
            int m = i >> 5, kk = i & 31;
            Xs[kk][m] = loadf(nf, (size_t)cais[m]*H_ + k0 + kk, f32);
        }
        for (int i = tid; i < 32*64; i += 256) {
            int kk = i >> 6, nn = i & 63;
            Wsh[kk][nn] = loadf(W, (size_t)(k0+kk)*H_ + ncol0 + nn, f32);
        }
        __syncthreads();
        for (int k = 0; k < 32; k++) {
            f32x4 a = *(const f32x4*)&Xs[k][tm*4];
            f32x4 b = *(const f32x4*)&Wsh[k][tn*4];
            #pragma unroll
            for (int i = 0; i < 4; i++)
                #pragma unroll
                for (int j = 0; j < 4; j++)
                    acc[i][j] += a[i] * b[j];
        }
    }
    const void* bias = (mat==0) ? bq : (mat==1) ? bk : bv;
    void* dst = (mat==0) ? qf : (mat==1) ? kf : vf;
    #pragma unroll
    for (int i = 0; i < 4; i++) {
        int m = mbase + tm*4 + i;
        #pragma unroll
        for (int j = 0; j < 4; j++) {
            int col = ncol0 + tn*4 + j;
            float val = acc[i][j] + loadf(bias, col, f32);
            if (qkvf32) ((float*)dst)[(size_t)m*H_ + col] = val;
            else        ((unsigned short*)dst)[(size_t)m*H_ + col] = f2bf(val);
        }
    }
}

// ---------------------------------------------------------------- attention v2 (2x2 + 4x4 blocking)
__global__ __launch_bounds__(256) void attn_tile2(
    const void* __restrict__ qf, const void* __restrict__ kf, const void* __restrict__ vf,
    const float* __restrict__ ca, const float* __restrict__ cb,
    const float* __restrict__ fr, const float* __restrict__ maskf,
    float* __restrict__ fa, int qkvf32)
{
    __shared__ __align__(16) float Qs[QT2][132];
    __shared__ __align__(16) float Ks[KT2][132];
    __shared__ __align__(16) float Vs[KT2][132];
    __shared__ __align__(16) float AshT[KT2][36];   // [k][q]
    __shared__ float caS[KT2][4];
    __shared__ float cbS[QT2][3];
    __shared__ float maskQ[QT2];
    __shared__ float red[QT2][16][4];
    __shared__ float invden[QT2];
    const int tid = threadIdx.x;
    const int qbase = blockIdx.x * QT2;
    const int h = blockIdx.y;
    // stage Q tile: 32x128 floats
    for (int i = tid; i < QT2*32; i += 256) {
        int q = i >> 5, d4 = i & 31;
        size_t base = (size_t)(qbase+q)*H_ + h*HD_ + d4*4;
        if (qkvf32) {
            *(f32x4*)&Qs[q][d4*4] = *(const f32x4*)((const float*)qf + base);
        } else {
            const unsigned short* qb = (const unsigned short*)qf;
            Qs[q][d4*4+0] = bf2f(qb[base+0]); Qs[q][d4*4+1] = bf2f(qb[base+1]);
            Qs[q][d4*4+2] = bf2f(qb[base+2]); Qs[q][d4*4+3] = bf2f(qb[base+3]);
        }
    }
    if (tid < QT2) {
        cbS[tid][0] = cb[(qbase+tid)*3+0];
        cbS[tid][1] = cb[(qbase+tid)*3+1];
        cbS[tid][2] = cb[(qbase+tid)*3+2];
        maskQ[tid] = maskf[qbase+tid];
    }
    // Phase A ids: q in {tq, tq+16}, k in {tk, tk+16}
    const int tq = tid & 15, tk = tid >> 4;
    // Phase B ids: 4q x 4d per thread
    const int tqg = tid >> 5, tdg = tid & 31;
    float pd[2][4] = {};       // per q-half: den, ax, ay, az
    float o[16] = {};
    for (int kt = 0; kt < R_/KT2; kt++) {
        const int kb = kt * KT2;
        __syncthreads();
        for (int i = tid; i < KT2*32; i += 256) {
            int k = i >> 5, d4 = i & 31;
            size_t base = (size_t)(kb+k)*H_ + h*HD_ + d4*4;
            if (qkvf32) {
                *(f32x4*)&Ks[k][d4*4] = *(const f32x4*)((const float*)kf + base);
                *(f32x4*)&Vs[k][d4*4] = *(const f32x4*)((const float*)vf + base);
            } else {
                const unsigned short* kbp = (const unsigned short*)kf;
                const unsigned short* vbp = (const unsigned short*)vf;
                #pragma unroll
                for (int e = 0; e < 4; e++) {
                    Ks[k][d4*4+e] = bf2f(kbp[base+e]);
                    Vs[k][d4*4+e] = bf2f(vbp[base+e]);
                }
            }
        }
        if (tid < KT2) {
            caS[tid][0] = ca[(kb+tid)*3+0];
            caS[tid][1] = ca[(kb+tid)*3+1];
            caS[tid][2] = ca[(kb+tid)*3+2];
            caS[tid][3] = maskf[kb+tid];
        }
        __syncthreads();
        // Phase A: 2x2 dots
        float dot[2][2] = {};
        for (int d4 = 0; d4 < 32; d4++) {
            f32x4 qa0 = *(const f32x4*)&Qs[tq][d4*4];
            f32x4 qa1 = *(const f32x4*)&Qs[tq+16][d4*4];
            f32x4 kv0 = *(const f32x4*)&Ks[tk][d4*4];
            f32x4 kv1 = *(const f32x4*)&Ks[tk+16][d4*4];
            #pragma unroll
            for (int e = 0; e < 4; e++) {
                dot[0][0] += qa0[e]*kv0[e];
                dot[0][1] += qa0[e]*kv1[e];
                dot[1][0] += qa1[e]*kv0[e];
                dot[1][1] += qa1[e]*kv1[e];
            }
        }
        #pragma unroll
        for (int iq = 0; iq < 2; iq++) {
            int q = tq + iq*16;
            float mq = (maskQ[q] > 0.f) ? 1.f : 0.f;
            #pragma unroll
            for (int ik = 0; ik < 2; ik++) {
                int k = tk + ik*16;
                float a = __expf(fminf(dot[iq][ik], 75.f)) * caS[k][3] * mq;
                if (!(a < 3.0e38f)) a = 0.f;
                pd[iq][0] += a;
                pd[iq][1] += a * caS[k][0];
                pd[iq][2] += a * caS[k][1];
                pd[iq][3] += a * caS[k][2];
                AshT[k][q] = a;
            }
        }
        __syncthreads();
        // Phase B: 4x4 o-accumulation
        for (int k = 0; k < KT2; k++) {
            f32x4 av = *(const f32x4*)&AshT[k][tqg*4];
            f32x4 vv = *(const f32x4*)&Vs[k][tdg*4];
            #pragma unroll
            for (int i = 0; i < 4; i++)
                #pragma unroll
                for (int j = 0; j < 4; j++)
                    o[i*4+j] += av[i] * vv[j];
        }
    }
    // reduce den/pos partials: thread (tq,tk) covers q = tq and tq+16
    #pragma unroll
    for (int c = 0; c < 4; c++) {
        red[tq][tk][c] = pd[0][c];
        red[tq+16][tk][c] = pd[1][c];
    }
    __syncthreads();
    if (tid < QT2) {
        float den=0.f, ax=0.f, ay=0.f, az=0.f;
        for (int g = 0; g < 16; g++) {
            den += red[tid][g][0]; ax += red[tid][g][1];
            ay  += red[tid][g][2]; az += red[tid][g][3];
        }
        float inv = (den > 0.f) ? 1.f/den : 0.f;
        invden[tid] = inv;
        float live = (den > 0.f) ? 1.f : 0.f;
        int qg = qbase + tid;
        float b0 = cbS[tid][0]*live - ax*inv;
        float b1 = cbS[tid][1]*live - ay*inv;
        float b2 = cbS[tid][2]*live - az*inv;
        float dist = sqrtf(b0*b0 + b1*b1 + b2*b2);
        const float* F = fr + (size_t)qg*9;
        float p0 = F[0]*b0 + F[1]*b1 + F[2]*b2;
        float p1 = F[3]*b0 + F[4]*b1 + F[5]*b2;
        float p2 = F[6]*b0 + F[7]*b1 + F[8]*b2;
        float pn = sqrtf(p0*p0 + p1*p1 + p2*p2) + 1e-10f;
        size_t rb = (size_t)qg * FA_LD;
        fa[rb + 512 + h*3 + 0] = p0;
        fa[rb + 512 + h*3 + 1] = p1;
        fa[rb + 512 + h*3 + 2] = p2;
        fa[rb + 524 + h]       = dist;
        fa[rb + 528 + h*3 + 0] = p0/pn;
        fa[rb + 528 + h*3 + 1] = p1/pn;
        fa[rb + 528 + h*3 + 2] = p2/pn;
        if (h == 0) { fa[rb+540]=0.f; fa[rb+541]=0.f; fa[rb+542]=0.f; fa[rb+543]=0.f; }
    }
    __syncthreads();
    // feat_node: q = tqg*4 + i, d = tdg*4 + j
    #pragma unroll
    for (int i = 0; i < 4; i++) {
        int q = tqg*4 + i;
        float inv = invden[q];
        size_t rowb = (size_t)(qbase+q)*FA_LD + h*HD_;
        #pragma unroll
        for (int j = 0; j < 4; j++)
            fa[rowb + tdg*4 + j] = o[i*4+j] * inv;
    }
}

// ---------------------------------------------------------------- Wo tiled GEMM (R16 verbatim)
__global__ __launch_bounds__(256) void wo_tile(
    const float* __restrict__ fa, const void* __restrict__ Wo,
    const void* __restrict__ bo, float* __restrict__ Y,
    const int* __restrict__ flag)
{
    __shared__ __align__(16) float Xs[32][68];   // [k][m]
    __shared__ __align__(16) float Wsh[32][68];  // [k][n]
    const int tid = threadIdx.x;
    const int mbase = blockIdx.x * 64;
    const int nbase = blockIdx.y * 64;
    bool f32 = *flag != 0;
    const int tm = tid >> 4, tn = tid & 15;
    float acc[4][4] = {};
    for (int kt = 0; kt < 17; kt++) {
        const int k0 = kt * 32;
        __syncthreads();
        for (int i = tid; i < 64*32; i += 256) {
            int m = i >> 5, kk = i & 31;
            Xs[kk][m] = fa[(size_t)(mbase+m)*FA_LD + k0 + kk];
        }
        for (int i = tid; i < 32*64; i += 256) {
            int kk = i >> 6, nn = i & 63;
            int krow = k0 + kk;
            Wsh[kk][nn] = (krow < 540) ? loadf(Wo, (size_t)krow*H_ + nbase + nn, f32) : 0.f;
        }
        __syncthreads();
        for (int k = 0; k < 32; k++) {
            f32x4 a = *(const f32x4*)&Xs[k][tm*4];
            f32x4 b = *(const f32x4*)&Wsh[k][tn*4];
            #pragma unroll
            for (int i = 0; i < 4; i++)
                #pragma unroll
                for (int j = 0; j < 4; j++)
                    acc[i][j] += a[i] * b[j];
        }
    }
    #pragma unroll
    for (int i = 0; i < 4; i++) {
        int m = mbase + tm*4 + i;
        #pragma unroll
        for (int j = 0; j < 4; j++) {
            int n = nbase + tn*4 + j;
            Y[(size_t)m*H_ + n] = acc[i][j] + loadf(bo, n, f32);
        }
    }
}

// ---------------------------------------------------------------- relu+LN1+mask+res+LN2 (R16 verbatim)
__global__ __launch_bounds__(256) void final_ln(
    const float* __restrict__ Y, const void* __restrict__ nf,
    const int* __restrict__ cai, const float* __restrict__ maskf,
    const void* __restrict__ g1, const void* __restrict__ b1,
    const void* __restrict__ g2, const void* __restrict__ b2,
    void* __restrict__ out, const int* __restrict__ flag)
{
    const int tid = threadIdx.x, lane = tid & 63, wave = tid >> 6;
    const int r = blockIdx.x * 4 + wave;
    bool f32 = *flag != 0;
    const float mk = maskf[r];
    const size_t xrow = (size_t)cai[r] * H_;
    float y[8], s1 = 0.f, s2 = 0.f;
    #pragma unroll
    for (int i = 0; i < 8; i++) {
        int c = lane + i*64;
        float v = fmaxf(Y[(size_t)r*H_ + c], 0.f);
        y[i] = v; s1 += v; s2 += v*v;
    }
    #pragma unroll
    for (int off = 32; off; off >>= 1) { s1 += __shfl_xor(s1, off); s2 += __shfl_xor(s2, off); }
    float mu = s1 * (1.f/H_);
    float var = s2 * (1.f/H_) - mu*mu;
    float rstd = rsqrtf(fmaxf(var, 0.f) + 1e-5f);
    float t[8], u1 = 0.f, u2 = 0.f;
    #pragma unroll
    for (int i = 0; i < 8; i++) {
        int c = lane + i*64;
        float hh = (y[i]-mu)*rstd*loadf(g1, c, f32) + loadf(b1, c, f32);
        hh *= mk;
        float tv = loadf(nf, xrow + c, f32) + hh;
        t[i] = tv; u1 += tv; u2 += tv*tv;
    }
    #pragma unroll
    for (int off = 32; off; off >>= 1) { u1 += __shfl_xor(u1, off); u2 += __shfl_xor(u2, off); }
    float mu2 = u1 * (1.f/H_);
    float var2 = u2 * (1.f/H_) - mu2*mu2;
    float rstd2 = rsqrtf(fmaxf(var2, 0.f) + 1e-5f);
    #pragma unroll
    for (int i = 0; i < 8; i++) {
        int c = lane + i*64;
        float ov = (t[i]-mu2)*rstd2*loadf(g2, c, f32) + loadf(b2, c, f32);
        if (f32) ((float*)out)[(size_t)r*H_ + c] = ov;
        else ((unsigned short*)out)[(size_t)r*H_ + c] = f2bf(ov);
    }
}

// ---------------------------------------------------------------- launch
extern "C" void kernel_launch(void* const* d_in, const int* in_sizes, int n_in,
                              void* d_out, int out_size, void* d_ws, size_t ws_size,
                              hipStream_t stream)
{
    static const int expected[16] = {
        8388608, 49152, 262144, 512, 262144, 512, 262144, 512,
        276480, 512, 512, 512, 512, 512, 16384, 16384
    };
    if (n_in != 16) {
        diag<<<dim3(1), dim3(64), 0, stream>>>((unsigned short*)d_out, 1000.f + n_in);
        return;
    }
    for (int i = 0; i < 16; i++) {
        if (in_sizes[i] != expected[i]) {
            diag<<<dim3(1), dim3(64), 0, stream>>>((unsigned short*)d_out, 2000.f + 10.f*i);
            return;
        }
    }
    const size_t smallEnd = 1u << 20;
    const size_t qkvF32Bytes = (size_t)R_*H_*4;
    const size_t qkvBF16Bytes = (size_t)R_*H_*2;
    const size_t faBytes = (size_t)R_*FA_LD*4;
    const size_t needF32  = smallEnd + 3*qkvF32Bytes + faBytes;
    const size_t needBF16 = smallEnd + 3*qkvBF16Bytes + faBytes;
    if (ws_size < needBF16) {
        diag<<<dim3(1), dim3(64), 0, stream>>>((unsigned short*)d_out, 3000.f);
        return;
    }
    const int qkvf32 = (ws_size >= needF32) ? 1 : 0;
    const size_t qkvBytes = qkvf32 ? qkvF32Bytes : qkvBF16Bytes;

    const void* nf  = d_in[0];
    const void* pos = d_in[1];
    const void* Wq  = d_in[2];  const void* bq = d_in[3];
    const void* Wk  = d_in[4];  const void* bk = d_in[5];
    const void* Wv  = d_in[6];  const void* bv = d_in[7];
    const void* Wo  = d_in[8];  const void* bo = d_in[9];
    const void* g1  = d_in[10]; const void* b1 = d_in[11];
    const void* g2  = d_in[12]; const void* b2 = d_in[13];
    const int* atype = (const int*)d_in[14];

    char* ws = (char*)d_ws;
    int*   flag  = (int*)  (ws + 0);
    int*   cai   = (int*)  (ws + 1024);
    float* ca    = (float*)(ws + 9216);
    float* cb    = (float*)(ws + 33792);
    float* fr    = (float*)(ws + 58368);
    float* maskf = (float*)(ws + 132096);
    void*  qf = ws + smallEnd;
    void*  kf = ws + smallEnd + qkvBytes;
    void*  vf = ws + smallEnd + 2*qkvBytes;
    float* fa = (float*)(ws + smallEnd + 3*qkvBytes);
    float* Y  = (float*)qf;   // aliases qf(+kf) — both dead after attn

    detect_dtype<<<dim3(1), dim3(256), 0, stream>>>((const unsigned short*)nf, flag);
    gather_frames<<<dim3(8), dim3(256), 0, stream>>>(pos, atype, flag, cai, ca, cb, fr, maskf);
    qkv_tile<<<dim3(R_/64, 24), dim3(256), 0, stream>>>(nf, cai, Wq, Wk, Wv, bq, bk, bv,
                                                        qf, kf, vf, flag, qkvf32);
    attn_tile2<<<dim3(R_/QT2, HEADS_), dim3(256), 0, stream>>>(qf, kf, vf, ca, cb, fr, maskf,
                                                               fa, qkvf32);
    wo_tile<<<dim3(R_/64, H_/64), dim3(256), 0, stream>>>(fa, Wo, bo, Y, flag);
    final_ln<<<dim3(512), dim3(256), 0, stream>>>(Y, nf, cai, maskf, g1, b1, g2, b2,
                                                  d_out, flag);
}

// Round 18
// 589.704 us; speedup vs baseline: 12.1869x; 1.0368x over previous
//
#include <hip/hip_runtime.h>
#include <hip/hip_bf16.h>
#include <stdint.h>

// GeometricGNN on MI355X. R=2048, APR=8, H=512, HEADS=4, HD=128, SD=28.
// Round 18: R17 (passing, 611us) with ONLY attn replaced by attn_tile3:
// KT=64 (half the barriers), Phase A 2qx4k (1.5 B/FLOP), Phase B 4x4 over
// 64 keys (1 B/FLOP), AshT padded [64][40] (2-way-max bank aliases).
// Everything else byte-identical to R17.

#define R_ 2048
#define APR_ 8
#define H_ 512
#define HEADS_ 4
#define HD_ 128
#define FA_LD 544
#define QT3 32
#define KT3 64

typedef __attribute__((ext_vector_type(4))) float f32x4;

static __device__ __forceinline__ float bf2f(unsigned short u) {
    union { unsigned int i; float f; } c; c.i = ((unsigned int)u) << 16; return c.f;
}
static __device__ __forceinline__ unsigned short f2bf(float f) {
    union { float f; unsigned int i; } c; c.f = f;
    unsigned int r = c.i + 0x7fffu + ((c.i >> 16) & 1u);   // RNE
    return (unsigned short)(r >> 16);
}
// flag-aware, sanitized load of logical element i of a float input array
static __device__ __forceinline__ float loadf(const void* p, size_t i, bool f32) {
    float v = f32 ? ((const float*)p)[i] : bf2f(((const unsigned short*)p)[i]);
    return (v == v && fabsf(v) < 1e30f) ? v : 0.f;
}

// ---------------------------------------------------------------- diag
__global__ void diag(unsigned short* out, float val) {
    if (threadIdx.x == 0 && blockIdx.x == 0) out[0] = f2bf(val);
}

// ---------------------------------------------------------------- dtype detect (d_in[0])
__global__ void detect_dtype(const unsigned short* __restrict__ nf, int* flag) {
    __shared__ int bad;
    if (threadIdx.x == 0) bad = 0;
    __syncthreads();
    int cnt = 0;
    for (int i = threadIdx.x; i < 8192; i += 256) {
        unsigned e = (nf[i] >> 7) & 0xFFu;
        if (e >= 0xC0u) cnt++;
    }
    atomicAdd(&bad, cnt);
    __syncthreads();
    if (threadIdx.x == 0) *flag = (bad > 16) ? 1 : 0;
}

// ---------------------------------------------------------------- gather + frames (R17 verbatim)
__global__ void gather_frames(const void* __restrict__ pos,
                              const int* __restrict__ atype,
                              const int* __restrict__ flag,
                              int* __restrict__ cai, float* __restrict__ ca,
                              float* __restrict__ cb, float* __restrict__ fr,
                              float* __restrict__ maskf)
{
    int r = blockIdx.x * blockDim.x + threadIdx.x;
    if (r >= R_) return;
    bool f32 = *flag != 0;
    int base = r * APR_;
    float caP[3] = {0,0,0}, cbP[3] = {0,0,0};
    int idx = base; bool h0=false, h1=false, h2=false;
    for (int a = 0; a < APR_; a++) {
        int t = atype[base + a];
        if (t == 0) h0 = true;
        if (t == 2) h2 = true;
        if (t == 1) { h1 = true; idx = base + a;
            for (int j = 0; j < 3; j++) caP[j] += loadf(pos, (size_t)(base+a)*3 + j, f32); }
        if (t == 4) {
            for (int j = 0; j < 3; j++) cbP[j] += loadf(pos, (size_t)(base+a)*3 + j, f32); }
    }
    float s = fabsf(cbP[0]) + fabsf(cbP[1]) + fabsf(cbP[2]);
    if (s < 1e-6f) { cbP[0]=caP[0]; cbP[1]=caP[1]; cbP[2]=caP[2]; }
    float e1[3] = { cbP[0]-caP[0], cbP[1]-caP[1], cbP[2]-caP[2] };
    float n1 = sqrtf(e1[0]*e1[0] + e1[1]*e1[1] + e1[2]*e1[2]);
    float e1u[3] = { e1[0], e1[1], e1[2] };
    if (n1 > 1e-6f) { float iv = 1.f / fmaxf(n1, 1e-6f); e1u[0]*=iv; e1u[1]*=iv; e1u[2]*=iv; }
    float e2a[3] = { e1u[1], -e1u[0], 0.f };
    float n2a = sqrtf(e2a[0]*e2a[0] + e2a[1]*e2a[1]);
    float e2b[3] = { -e1u[2], 0.f, e1u[0] };
    float n2b = sqrtf(e2b[0]*e2b[0] + e2b[2]*e2b[2]);
    bool useb = n2a < 1e-6f;
    float e2[3] = { useb?e2b[0]:e2a[0], useb?e2b[1]:e2a[1], useb?e2b[2]:e2a[2] };
    float n2 = useb ? n2b : n2a;
    float iv2 = 1.f / fmaxf(n2, 1e-6f);
    float e2u[3] = { e2[0]*iv2, e2[1]*iv2, e2[2]*iv2 };
    float e3[3] = { e1u[1]*e2u[2]-e1u[2]*e2u[1],
                    e1u[2]*e2u[0]-e1u[0]*e2u[2],
                    e1u[0]*e2u[1]-e1u[1]*e2u[0] };
    bool ok = (r < R_-1) && (n1 > 1e-6f) && (n2 > 1e-6f);
    float F[9];
    if (ok) { F[0]=e1u[0]; F[1]=e2u[0]; F[2]=e3[0];
              F[3]=e1u[1]; F[4]=e2u[1]; F[5]=e3[1];
              F[6]=e1u[2]; F[7]=e2u[2]; F[8]=e3[2]; }
    else    { F[0]=1;F[1]=0;F[2]=0; F[3]=0;F[4]=1;F[5]=0; F[6]=0;F[7]=0;F[8]=1; }
    cai[r] = idx;
    for (int j = 0; j < 3; j++) { ca[r*3+j] = caP[j]; cb[r*3+j] = cbP[j]; }
    for (int j = 0; j < 9; j++) fr[r*9+j] = F[j];
    maskf[r] = (h0 && h1 && h2) ? 1.f : 0.f;
}

// ---------------------------------------------------------------- QKV tiled GEMM (R17 verbatim)
__global__ __launch_bounds__(256) void qkv_tile(
    const void* __restrict__ nf, const int* __restrict__ cai,
    const void* __restrict__ Wq, const void* __restrict__ Wk, const void* __restrict__ Wv,
    const void* __restrict__ bq, const void* __restrict__ bk, const void* __restrict__ bv,
    void* __restrict__ qf, void* __restrict__ kf, void* __restrict__ vf,
    const int* __restrict__ flag, int qkvf32)
{
    __shared__ __align__(16) float Xs[32][68];   // [k][m]
    __shared__ __align__(16) float Wsh[32][68];  // [k][n]
    __shared__ int cais[64];
    const int tid = threadIdx.x;
    const int mbase = blockIdx.x * 64;
    const int nblk  = blockIdx.y * 64;           // 0..1535
    const int mat   = nblk >> 9;
    const int ncol0 = nblk & 511;
    bool f32 = *flag != 0;
    const void* W = (mat==0) ? Wq : (mat==1) ? Wk : Wv;
    const int tm = tid >> 4, tn = tid & 15;
    float acc[4][4] = {};
    if (tid < 64) cais[tid] = cai[mbase + tid];
    for (int kt = 0; kt < 16; kt++) {
        const int k0 = kt * 32;
        __syncthreads();   // prior iter reads done; iter0: cais visible
        for (int i = tid; i < 64*32; i += 256) {
            int m = i >> 5, kk = i & 31;
            Xs[kk][m] = loadf(nf, (size_t)cais[m]*H_ + k0 + kk, f32);
        }
        for (int i = tid; i < 32*64; i += 256) {
            int kk = i >> 6, nn = i & 63;
            Wsh[kk][nn] = loadf(W, (size_t)(k0+kk)*H_ + ncol0 + nn, f32);
        }
        __syncthreads();
        for (int k = 0; k < 32; k++) {
            f32x4 a = *(const f32x4*)&Xs[k][tm*4];
            f32x4 b = *(const f32x4*)&Wsh[k][tn*4];
            #pragma unroll
            for (int i = 0; i < 4; i++)
                #pragma unroll
                for (int j = 0; j < 4; j++)
                    acc[i][j] += a[i] * b[j];
        }
    }
    const void* bias = (mat==0) ? bq : (mat==1) ? bk : bv;
    void* dst = (mat==0) ? qf : (mat==1) ? kf : vf;
    #pragma unroll
    for (int i = 0; i < 4; i++) {
        int m = mbase + tm*4 + i;
        #pragma unroll
        for (int j = 0; j < 4; j++) {
            int col = ncol0 + tn*4 + j;
            float val = acc[i][j] + loadf(bias, col, f32);
            if (qkvf32) ((float*)dst)[(size_t)m*H_ + col] = val;
            else        ((unsigned short*)dst)[(size_t)m*H_ + col] = f2bf(val);
        }
    }
}

// ---------------------------------------------------------------- attention v3 (KT=64, 2x4 A, 4x4 B)
__global__ __launch_bounds__(256) void attn_tile3(
    const void* __restrict__ qf, const void* __restrict__ kf, const void* __restrict__ vf,
    const float* __restrict__ ca, const float* __restrict__ cb,
    const float* __restrict__ fr, const float* __restrict__ maskf,
    float* __restrict__ fa, int qkvf32)
{
    __shared__ __align__(16) float Qs[QT3][132];
    __shared__ __align__(16) float Ks[KT3][132];
    __shared__ __align__(16) float Vs[KT3][132];
    __shared__ __align__(16) float AshT[KT3][40];   // [k][q], pad 40 -> <=2-way aliases
    __shared__ float caS[KT3][4];
    __shared__ float cbS[QT3][3];
    __shared__ float maskQ[QT3];
    __shared__ float red[QT3][16][4];
    __shared__ float invden[QT3];
    const int tid = threadIdx.x;
    const int qbase = blockIdx.x * QT3;
    const int h = blockIdx.y;
    // stage Q tile: 32x128 floats
    for (int i = tid; i < QT3*32; i += 256) {
        int q = i >> 5, d4 = i & 31;
        size_t base = (size_t)(qbase+q)*H_ + h*HD_ + d4*4;
        if (qkvf32) {
            *(f32x4*)&Qs[q][d4*4] = *(const f32x4*)((const float*)qf + base);
        } else {
            const unsigned short* qb = (const unsigned short*)qf;
            Qs[q][d4*4+0] = bf2f(qb[base+0]); Qs[q][d4*4+1] = bf2f(qb[base+1]);
            Qs[q][d4*4+2] = bf2f(qb[base+2]); Qs[q][d4*4+3] = bf2f(qb[base+3]);
        }
    }
    if (tid < QT3) {
        cbS[tid][0] = cb[(qbase+tid)*3+0];
        cbS[tid][1] = cb[(qbase+tid)*3+1];
        cbS[tid][2] = cb[(qbase+tid)*3+2];
        maskQ[tid] = maskf[qbase+tid];
    }
    // Phase A ids: q in {tq, tq+16}; k in {tk, tk+16, tk+32, tk+48}
    const int tq = tid & 15, tk = tid >> 4;
    // Phase B ids: q = tqg*4+i, d = tdg*4+j
    const int tqg = tid >> 5, tdg = tid & 31;
    float pd[2][4] = {};       // per q-half: den, ax, ay, az
    float o[16] = {};
    for (int kt = 0; kt < R_/KT3; kt++) {
        const int kb = kt * KT3;
        __syncthreads();
        for (int i = tid; i < KT3*32; i += 256) {
            int k = i >> 5, d4 = i & 31;
            size_t base = (size_t)(kb+k)*H_ + h*HD_ + d4*4;
            if (qkvf32) {
                *(f32x4*)&Ks[k][d4*4] = *(const f32x4*)((const float*)kf + base);
                *(f32x4*)&Vs[k][d4*4] = *(const f32x4*)((const float*)vf + base);
            } else {
                const unsigned short* kbp = (const unsigned short*)kf;
                const unsigned short* vbp = (const unsigned short*)vf;
                #pragma unroll
                for (int e = 0; e < 4; e++) {
                    Ks[k][d4*4+e] = bf2f(kbp[base+e]);
                    Vs[k][d4*4+e] = bf2f(vbp[base+e]);
                }
            }
        }
        if (tid < KT3) {
            caS[tid][0] = ca[(kb+tid)*3+0];
            caS[tid][1] = ca[(kb+tid)*3+1];
            caS[tid][2] = ca[(kb+tid)*3+2];
            caS[tid][3] = maskf[kb+tid];
        }
        __syncthreads();
        // Phase A: 2x4 dots
        float dot[2][4] = {};
        for (int d4 = 0; d4 < 32; d4++) {
            f32x4 qa0 = *(const f32x4*)&Qs[tq][d4*4];
            f32x4 qa1 = *(const f32x4*)&Qs[tq+16][d4*4];
            #pragma unroll
            for (int ik = 0; ik < 4; ik++) {
                f32x4 kv = *(const f32x4*)&Ks[tk + ik*16][d4*4];
                #pragma unroll
                for (int e = 0; e < 4; e++) {
                    dot[0][ik] += qa0[e]*kv[e];
                    dot[1][ik] += qa1[e]*kv[e];
                }
            }
        }
        #pragma unroll
        for (int iq = 0; iq < 2; iq++) {
            int q = tq + iq*16;
            float mq = (maskQ[q] > 0.f) ? 1.f : 0.f;
            #pragma unroll
            for (int ik = 0; ik < 4; ik++) {
                int k = tk + ik*16;
                float a = __expf(fminf(dot[iq][ik], 75.f)) * caS[k][3] * mq;
                if (!(a < 3.0e38f)) a = 0.f;
                pd[iq][0] += a;
                pd[iq][1] += a * caS[k][0];
                pd[iq][2] += a * caS[k][1];
                pd[iq][3] += a * caS[k][2];
                AshT[k][q] = a;
            }
        }
        __syncthreads();
        // Phase B: 4x4 o-accumulation over 64 keys
        for (int k = 0; k < KT3; k++) {
            f32x4 av = *(const f32x4*)&AshT[k][tqg*4];
            f32x4 vv = *(const f32x4*)&Vs[k][tdg*4];
            #pragma unroll
            for (int i = 0; i < 4; i++)
                #pragma unroll
                for (int j = 0; j < 4; j++)
                    o[i*4+j] += av[i] * vv[j];
        }
    }
    // reduce den/pos partials: thread (tq,tk) covers q = tq and tq+16
    #pragma unroll
    for (int c = 0; c < 4; c++) {
        red[tq][tk][c] = pd[0][c];
        red[tq+16][tk][c] = pd[1][c];
    }
    __syncthreads();
    if (tid < QT3) {
        float den=0.f, ax=0.f, ay=0.f, az=0.f;
        for (int g = 0; g < 16; g++) {
            den += red[tid][g][0]; ax += red[tid][g][1];
            ay  += red[tid][g][2]; az += red[tid][g][3];
        }
        float inv = (den > 0.f) ? 1.f/den : 0.f;
        invden[tid] = inv;
        float live = (den > 0.f) ? 1.f : 0.f;
        int qg = qbase + tid;
        float b0 = cbS[tid][0]*live - ax*inv;
        float b1 = cbS[tid][1]*live - ay*inv;
        float b2 = cbS[tid][2]*live - az*inv;
        float dist = sqrtf(b0*b0 + b1*b1 + b2*b2);
        const float* F = fr + (size_t)qg*9;
        float p0 = F[0]*b0 + F[1]*b1 + F[2]*b2;
        float p1 = F[3]*b0 + F[4]*b1 + F[5]*b2;
        float p2 = F[6]*b0 + F[7]*b1 + F[8]*b2;
        float pn = sqrtf(p0*p0 + p1*p1 + p2*p2) + 1e-10f;
        size_t rb = (size_t)qg * FA_LD;
        fa[rb + 512 + h*3 + 0] = p0;
        fa[rb + 512 + h*3 + 1] = p1;
        fa[rb + 512 + h*3 + 2] = p2;
        fa[rb + 524 + h]       = dist;
        fa[rb + 528 + h*3 + 0] = p0/pn;
        fa[rb + 528 + h*3 + 1] = p1/pn;
        fa[rb + 528 + h*3 + 2] = p2/pn;
        if (h == 0) { fa[rb+540]=0.f; fa[rb+541]=0.f; fa[rb+542]=0.f; fa[rb+543]=0.f; }
    }
    __syncthreads();
    // feat_node: q = tqg*4 + i, d = tdg*4 + j
    #pragma unroll
    for (int i = 0; i < 4; i++) {
        int q = tqg*4 + i;
        float inv = invden[q];
        size_t rowb = (size_t)(qbase+q)*FA_LD + h*HD_;
        #pragma unroll
        for (int j = 0; j < 4; j++)
            fa[rowb + tdg*4 + j] = o[i*4+j] * inv;
    }
}

// ---------------------------------------------------------------- Wo tiled GEMM (R17 verbatim)
__global__ __launch_bounds__(256) void wo_tile(
    const float* __restrict__ fa, const void* __restrict__ Wo,
    const void* __restrict__ bo, float* __restrict__ Y,
    const int* __restrict__ flag)
{
    __shared__ __align__(16) float Xs[32][68];   // [k][m]
    __shared__ __align__(16) float Wsh[32][68];  // [k][n]
    const int tid = threadIdx.x;
    const int mbase = blockIdx.x * 64;
    const int nbase = blockIdx.y * 64;
    bool f32 = *flag != 0;
    const int tm = tid >> 4, tn = tid & 15;
    float acc[4][4] = {};
    for (int kt = 0; kt < 17; kt++) {
        const int k0 = kt * 32;
        __syncthreads();
        for (int i = tid; i < 64*32; i += 256) {
            int m = i >> 5, kk = i & 31;
            Xs[kk][m] = fa[(size_t)(mbase+m)*FA_LD + k0 + kk];
        }
        for (int i = tid; i < 32*64; i += 256) {
            int kk = i >> 6, nn = i & 63;
            int krow = k0 + kk;
            Wsh[kk][nn] = (krow < 540) ? loadf(Wo, (size_t)krow*H_ + nbase + nn, f32) : 0.f;
        }
        __syncthreads();
        for (int k = 0; k < 32; k++) {
            f32x4 a = *(const f32x4*)&Xs[k][tm*4];
            f32x4 b = *(const f32x4*)&Wsh[k][tn*4];
            #pragma unroll
            for (int i = 0; i < 4; i++)
                #pragma unroll
                for (int j = 0; j < 4; j++)
                    acc[i][j] += a[i] * b[j];
        }
    }
    #pragma unroll
    for (int i = 0; i < 4; i++) {
        int m = mbase + tm*4 + i;
        #pragma unroll
        for (int j = 0; j < 4; j++) {
            int n = nbase + tn*4 + j;
            Y[(size_t)m*H_ + n] = acc[i][j] + loadf(bo, n, f32);
        }
    }
}

// ---------------------------------------------------------------- relu+LN1+mask+res+LN2 (R17 verbatim)
__global__ __launch_bounds__(256) void final_ln(
    const float* __restrict__ Y, const void* __restrict__ nf,
    const int* __restrict__ cai, const float* __restrict__ maskf,
    const void* __restrict__ g1, const void* __restrict__ b1,
    const void* __restrict__ g2, const void* __restrict__ b2,
    void* __restrict__ out, const int* __restrict__ flag)
{
    const int tid = threadIdx.x, lane = tid & 63, wave = tid >> 6;
    const int r = blockIdx.x * 4 + wave;
    bool f32 = *flag != 0;
    const float mk = maskf[r];
    const size_t xrow = (size_t)cai[r] * H_;
    float y[8], s1 = 0.f, s2 = 0.f;
    #pragma unroll
    for (int i = 0; i < 8; i++) {
        int c = lane + i*64;
        float v = fmaxf(Y[(size_t)r*H_ + c], 0.f);
        y[i] = v; s1 += v; s2 += v*v;
    }
    #pragma unroll
    for (int off = 32; off; off >>= 1) { s1 += __shfl_xor(s1, off); s2 += __shfl_xor(s2, off); }
    float mu = s1 * (1.f/H_);
    float var = s2 * (1.f/H_) - mu*mu;
    float rstd = rsqrtf(fmaxf(var, 0.f) + 1e-5f);
    float t[8], u1 = 0.f, u2 = 0.f;
    #pragma unroll
    for (int i = 0; i < 8; i++) {
        int c = lane + i*64;
        float hh = (y[i]-mu)*rstd*loadf(g1, c, f32) + loadf(b1, c, f32);
        hh *= mk;
        float tv = loadf(nf, xrow + c, f32) + hh;
        t[i] = tv; u1 += tv; u2 += tv*tv;
    }
    #pragma unroll
    for (int off = 32; off; off >>= 1) { u1 += __shfl_xor(u1, off); u2 += __shfl_xor(u2, off); }
    float mu2 = u1 * (1.f/H_);
    float var2 = u2 * (1.f/H_) - mu2*mu2;
    float rstd2 = rsqrtf(fmaxf(var2, 0.f) + 1e-5f);
    #pragma unroll
    for (int i = 0; i < 8; i++) {
        int c = lane + i*64;
        float ov = (t[i]-mu2)*rstd2*loadf(g2, c, f32) + loadf(b2, c, f32);
        if (f32) ((float*)out)[(size_t)r*H_ + c] = ov;
        else ((unsigned short*)out)[(size_t)r*H_ + c] = f2bf(ov);
    }
}

// ---------------------------------------------------------------- launch
extern "C" void kernel_launch(void* const* d_in, const int* in_sizes, int n_in,
                              void* d_out, int out_size, void* d_ws, size_t ws_size,
                              hipStream_t stream)
{
    static const int expected[16] = {
        8388608, 49152, 262144, 512, 262144, 512, 262144, 512,
        276480, 512, 512, 512, 512, 512, 16384, 16384
    };
    if (n_in != 16) {
        diag<<<dim3(1), dim3(64), 0, stream>>>((unsigned short*)d_out, 1000.f + n_in);
        return;
    }
    for (int i = 0; i < 16; i++) {
        if (in_sizes[i] != expected[i]) {
            diag<<<dim3(1), dim3(64), 0, stream>>>((unsigned short*)d_out, 2000.f + 10.f*i);
            return;
        }
    }
    const size_t smallEnd = 1u << 20;
    const size_t qkvF32Bytes = (size_t)R_*H_*4;
    const size_t qkvBF16Bytes = (size_t)R_*H_*2;
    const size_t faBytes = (size_t)R_*FA_LD*4;
    const size_t needF32  = smallEnd + 3*qkvF32Bytes + faBytes;
    const size_t needBF16 = smallEnd + 3*qkvBF16Bytes + faBytes;
    if (ws_size < needBF16) {
        diag<<<dim3(1), dim3(64), 0, stream>>>((unsigned short*)d_out, 3000.f);
        return;
    }
    const int qkvf32 = (ws_size >= needF32) ? 1 : 0;
    const size_t qkvBytes = qkvf32 ? qkvF32Bytes : qkvBF16Bytes;

    const void* nf  = d_in[0];
    const void* pos = d_in[1];
    const void* Wq  = d_in[2];  const void* bq = d_in[3];
    const void* Wk  = d_in[4];  const void* bk = d_in[5];
    const void* Wv  = d_in[6];  const void* bv = d_in[7];
    const void* Wo  = d_in[8];  const void* bo = d_in[9];
    const void* g1  = d_in[10]; const void* b1 = d_in[11];
    const void* g2  = d_in[12]; const void* b2 = d_in[13];
    const int* atype = (const int*)d_in[14];

    char* ws = (char*)d_ws;
    int*   flag  = (int*)  (ws + 0);
    int*   cai   = (int*)  (ws + 1024);
    float* ca    = (float*)(ws + 9216);
    float* cb    = (float*)(ws + 33792);
    float* fr    = (float*)(ws + 58368);
    float* maskf = (float*)(ws + 132096);
    void*  qf = ws + smallEnd;
    void*  kf = ws + smallEnd + qkvBytes;
    void*  vf = ws + smallEnd + 2*qkvBytes;
    float* fa = (float*)(ws + smallEnd + 3*qkvBytes);
    float* Y  = (float*)qf;   // aliases qf(+kf) — both dead after attn

    detect_dtype<<<dim3(1), dim3(256), 0, stream>>>((const unsigned short*)nf, flag);
    gather_frames<<<dim3(8), dim3(256), 0, stream>>>(pos, atype, flag, cai, ca, cb, fr, maskf);
    qkv_tile<<<dim3(R_/64, 24), dim3(256), 0, stream>>>(nf, cai, Wq, Wk, Wv, bq, bk, bv,
                                                        qf, kf, vf, flag, qkvf32);
    attn_tile3<<<dim3(R_/QT3, HEADS_), dim3(256), 0, stream>>>(qf, kf, vf, ca, cb, fr, maskf,
                                                               fa, qkvf32);
    wo_tile<<<dim3(R_/64, H_/64), dim3(256), 0, stream>>>(fa, Wo, bo, Y, flag);
    final_ln<<<dim3(512), dim3(256), 0, stream>>>(Y, nf, cai, maskf, g1, b1, g2, b2,
                                                  d_out, flag);
}